// Round 3
// baseline (3728.386 us; speedup 1.0000x reference)
//
#include <hip/hip_runtime.h>

// LSTM_84344567759011: 3-layer LSTM (B=16384, T=200, F=10, H=30) + FC(30->1), fp32.
//
// Round 3: layer-pipelined phases. Phase p computes L1(t=p), L2(t=p-1),
// L3(t=p-2) -- mutually independent within a phase -> ONE barrier per phase
// (202 total vs 600). All reads come from the previous phase's writes
// (parity ping-pong: write p&1, read (p&1)^1). h1/h2 vectors are shared
// between adjacent layers' GEMMs (90 LDS reads/thread/phase vs 150).
// Structure per phase: S0: L1 x-part (+x(p+1) prefetch into dead xv regs);
// S1: load h1 -> L1 h-part + L2 first half; S2: load h2 -> L2 second half +
// L3 first half; S3: load h3 -> L3 second half; then 3 thread-local gate
// updates, h writes, one barrier. Weights stream on the scalar pipe
// (wave-uniform rows). 256 blocks x 1024 threads, lane=batch, wave=2 units.

#define LOG2E 1.44269504088896340736f

static constexpr int B = 16384;
static constexpr int T = 200;
static constexpr int F = 10;
static constexpr int H = 30;

static constexpr int W1_OFF = 0;       // [128][40]
static constexpr int W2_OFF = 5120;    // [128][60]
static constexpr int W3_OFF = 12800;   // [128][60]
static constexpr int B1_OFF = 20480;   // [128]
static constexpr int B2_OFF = 20608;
static constexpr int B3_OFF = 20736;
static constexpr int WFC_OFF = 20864;
static constexpr int BFC_OFF = 20894;

__device__ float g_w[20896];

// packed row pr (0..127): wv = pr>>3, idx = pr&7, gate g = idx>>1, u = idx&1
// source unit j = wv*2+u (valid if j<30), source row sr = g*30 + j.
__global__ void lstm_prep(const float* __restrict__ Wih1, const float* __restrict__ Whh1,
                          const float* __restrict__ bih1, const float* __restrict__ bhh1,
                          const float* __restrict__ Wih2, const float* __restrict__ Whh2,
                          const float* __restrict__ bih2, const float* __restrict__ bhh2,
                          const float* __restrict__ Wih3, const float* __restrict__ Whh3,
                          const float* __restrict__ bih3, const float* __restrict__ bhh3,
                          const float* __restrict__ Wfc, const float* __restrict__ bfc) {
  const int tid = threadIdx.x;  // 256 threads, 1 block
  for (int idx = tid; idx < 128 * 40; idx += 256) {
    int pr = idx / 40, k = idx - pr * 40;
    int wv = pr >> 3, g = (pr >> 1) & 3, u = pr & 1;
    int j = wv * 2 + u;
    float v = 0.f;
    if (j < H) {
      int sr = g * H + j;
      v = (k < F) ? Wih1[sr * F + k] : Whh1[sr * H + (k - F)];
    }
    g_w[W1_OFF + idx] = v;
  }
  for (int idx = tid; idx < 128 * 60; idx += 256) {
    int pr = idx / 60, k = idx - pr * 60;
    int wv = pr >> 3, g = (pr >> 1) & 3, u = pr & 1;
    int j = wv * 2 + u;
    float v2 = 0.f, v3 = 0.f;
    if (j < H) {
      int sr = g * H + j;
      v2 = (k < H) ? Wih2[sr * H + k] : Whh2[sr * H + (k - H)];
      v3 = (k < H) ? Wih3[sr * H + k] : Whh3[sr * H + (k - H)];
    }
    g_w[W2_OFF + idx] = v2;
    g_w[W3_OFF + idx] = v3;
  }
  for (int pr = tid; pr < 128; pr += 256) {
    int wv = pr >> 3, g = (pr >> 1) & 3, u = pr & 1;
    int j = wv * 2 + u;
    float v1 = 0.f, v2 = 0.f, v3 = 0.f;
    if (j < H) {
      int sr = g * H + j;
      v1 = bih1[sr] + bhh1[sr];
      v2 = bih2[sr] + bhh2[sr];
      v3 = bih3[sr] + bhh3[sr];
    }
    g_w[B1_OFF + pr] = v1;
    g_w[B2_OFF + pr] = v2;
    g_w[B3_OFF + pr] = v3;
  }
  if (tid < H) g_w[WFC_OFF + tid] = Wfc[tid];
  if (tid == 0) g_w[BFC_OFF] = bfc[0];
}

__device__ __forceinline__ float sigx(float x) {
  return __builtin_amdgcn_rcpf(1.f + __builtin_amdgcn_exp2f(-x * LOG2E));
}
__device__ __forceinline__ float tanhx(float x) {
  float e = __builtin_amdgcn_exp2f(-x * (2.f * LOG2E));
  return fmaf(2.f, __builtin_amdgcn_rcpf(1.f + e), -1.f);
}

__device__ __forceinline__ void upd(const float* z, float* c, float* hw, int wv) {
#pragma unroll
  for (int u = 0; u < 2; ++u) {
    float ii = sigx(z[u]);
    float ff = sigx(z[2 + u]);
    float gg = tanhx(z[4 + u]);
    float oo = sigx(z[6 + u]);
    float cc = fmaf(ff, c[u], ii * gg);
    c[u] = cc;
    hw[wv * 2 + u] = oo * tanhx(cc);
  }
}

static constexpr int HP = 64 * 33;  // one parity buffer, floats

// Phase p: L1(t=p) if L1A, L2(t=p-1) if L2A, L3(t=p-2) if L3A.
// PF: prefetch x(p+1) into xv (after its last use).
template <bool L1A, bool L2A, bool L3A, bool PF>
__device__ __forceinline__ void do_phase(int p, int b, int wv,
                                         const float* __restrict__ xb,
                                         float* xv,
                                         float* c1, float* c2, float* c3,
                                         float* __restrict__ hs) {
  const int wp = p & 1, rp = wp ^ 1;
  const int rb = wv * 8;
  float z1[8], z2[8], z3[8];

  // ---- S0: L1 x-part
  if (L1A) {
#pragma unroll
    for (int r = 0; r < 8; ++r) {
      const float* wr = g_w + W1_OFF + (rb + r) * 40;
      float a = g_w[B1_OFF + rb + r];
#pragma unroll
      for (int k = 0; k < F; ++k) a = fmaf(wr[k], xv[k], a);
      z1[r] = a;
    }
  }
  if (PF) {  // xv dead now; reload with x(p+1), latency hides under S1-S3
#pragma unroll
    for (int i = 0; i < 5; ++i) {
      float2 t2 = *(const float2*)(xb + (p + 1) * F + i * 2);
      xv[2 * i] = t2.x;
      xv[2 * i + 1] = t2.y;
    }
  }
  if (L2A) {
#pragma unroll
    for (int r = 0; r < 8; ++r) z2[r] = g_w[B2_OFF + rb + r];
  }
  if (L3A) {
#pragma unroll
    for (int r = 0; r < 8; ++r) z3[r] = g_w[B3_OFF + rb + r];
  }

  // ---- S1: h1 -> L1 h-part + L2 first half
  if (L1A || L2A) {
    const float* h1r = hs + (0 * 2 + rp) * HP + b * 33;
    float hv[30];
#pragma unroll
    for (int k = 0; k < H; ++k) hv[k] = h1r[k];
    if (L1A) {
#pragma unroll
      for (int r = 0; r < 8; ++r) {
        const float* wr = g_w + W1_OFF + (rb + r) * 40 + F;
        float a = z1[r];
#pragma unroll
        for (int k = 0; k < H; ++k) a = fmaf(wr[k], hv[k], a);
        z1[r] = a;
      }
    }
    if (L2A) {
#pragma unroll
      for (int r = 0; r < 8; ++r) {
        const float* wr = g_w + W2_OFF + (rb + r) * 60;
        float a = z2[r];
#pragma unroll
        for (int k = 0; k < H; ++k) a = fmaf(wr[k], hv[k], a);
        z2[r] = a;
      }
    }
  }

  // ---- S2: h2 -> L2 second half + L3 first half
  if (L2A || L3A) {
    const float* h2r = hs + (1 * 2 + rp) * HP + b * 33;
    float hv[30];
#pragma unroll
    for (int k = 0; k < H; ++k) hv[k] = h2r[k];
    if (L2A) {
#pragma unroll
      for (int r = 0; r < 8; ++r) {
        const float* wr = g_w + W2_OFF + (rb + r) * 60 + H;
        float a = z2[r];
#pragma unroll
        for (int k = 0; k < H; ++k) a = fmaf(wr[k], hv[k], a);
        z2[r] = a;
      }
    }
    if (L3A) {
#pragma unroll
      for (int r = 0; r < 8; ++r) {
        const float* wr = g_w + W3_OFF + (rb + r) * 60;
        float a = z3[r];
#pragma unroll
        for (int k = 0; k < H; ++k) a = fmaf(wr[k], hv[k], a);
        z3[r] = a;
      }
    }
  }

  // ---- S3: h3 -> L3 second half
  if (L3A) {
    const float* h3r = hs + (2 * 2 + rp) * HP + b * 33;
    float hv[30];
#pragma unroll
    for (int k = 0; k < H; ++k) hv[k] = h3r[k];
#pragma unroll
    for (int r = 0; r < 8; ++r) {
      const float* wr = g_w + W3_OFF + (rb + r) * 60 + H;
      float a = z3[r];
#pragma unroll
      for (int k = 0; k < H; ++k) a = fmaf(wr[k], hv[k], a);
      z3[r] = a;
    }
  }

  // ---- updates (thread-local) + h writes
  if (L1A) upd(z1, c1, hs + (0 * 2 + wp) * HP + b * 33, wv);
  if (L2A) upd(z2, c2, hs + (1 * 2 + wp) * HP + b * 33, wv);
  if (L3A) upd(z3, c3, hs + (2 * 2 + wp) * HP + b * 33, wv);

  __syncthreads();
}

__global__ __launch_bounds__(1024, 4) void lstm_main(const float* __restrict__ x,
                                                     float* __restrict__ out) {
  __shared__ float h_s[3 * 2 * HP];  // [layer][parity][b][33], pitch 33

  const int tid = threadIdx.x;
  const int b = tid & 63;                                   // batch lane
  const int wv = __builtin_amdgcn_readfirstlane(tid >> 6);  // wave 0..15
  const int b0 = blockIdx.x * 64;

  for (int i = tid; i < 3 * 2 * HP; i += 1024) h_s[i] = 0.f;
  float c1[2] = {0.f, 0.f};
  float c2[2] = {0.f, 0.f};
  float c3[2] = {0.f, 0.f};

  const float* xb = x + (size_t)(b0 + b) * (T * F);
  float xv[F];
#pragma unroll
  for (int i = 0; i < 5; ++i) {
    float2 t2 = *(const float2*)(xb + i * 2);
    xv[2 * i] = t2.x;
    xv[2 * i + 1] = t2.y;
  }

  __syncthreads();

  // Phases: p=0..201. L1 on p<=199 (t=p), L2 on 1<=p<=200 (t=p-1),
  // L3 on 2<=p<=201 (t=p-2). Prefetch x(p+1) while p<199.
  do_phase<true, false, false, true>(0, b, wv, xb, xv, c1, c2, c3, h_s);
  do_phase<true, true, false, true>(1, b, wv, xb, xv, c1, c2, c3, h_s);
  for (int p = 2; p < 199; ++p)
    do_phase<true, true, true, true>(p, b, wv, xb, xv, c1, c2, c3, h_s);
  do_phase<true, true, true, false>(199, b, wv, xb, xv, c1, c2, c3, h_s);
  do_phase<false, true, true, false>(200, b, wv, xb, xv, c1, c2, c3, h_s);
  do_phase<false, false, true, false>(201, b, wv, xb, xv, c1, c2, c3, h_s);

  // ---- FC epilogue: out[b] = h3(199) . Wfc + bfc.
  // h3(199) written in phase 201, parity 201&1 = 1.
  if (wv == 0) {
    const float* h3 = h_s + (2 * 2 + 1) * HP + b * 33;
    float acc = g_w[BFC_OFF];
#pragma unroll
    for (int k = 0; k < H; ++k) acc = fmaf(h3[k], g_w[WFC_OFF + k], acc);
    out[b0 + b] = acc;
  }
}

extern "C" void kernel_launch(void* const* d_in, const int* in_sizes, int n_in,
                              void* d_out, int out_size, void* d_ws, size_t ws_size,
                              hipStream_t stream) {
  const float* x = (const float*)d_in[0];
  const float* Wih1 = (const float*)d_in[1];
  const float* Whh1 = (const float*)d_in[2];
  const float* bih1 = (const float*)d_in[3];
  const float* bhh1 = (const float*)d_in[4];
  const float* Wih2 = (const float*)d_in[5];
  const float* Whh2 = (const float*)d_in[6];
  const float* bih2 = (const float*)d_in[7];
  const float* bhh2 = (const float*)d_in[8];
  const float* Wih3 = (const float*)d_in[9];
  const float* Whh3 = (const float*)d_in[10];
  const float* bih3 = (const float*)d_in[11];
  const float* bhh3 = (const float*)d_in[12];
  const float* Wfc = (const float*)d_in[13];
  const float* bfc = (const float*)d_in[14];
  float* out = (float*)d_out;

  hipLaunchKernelGGL(lstm_prep, dim3(1), dim3(256), 0, stream,
                     Wih1, Whh1, bih1, bhh1, Wih2, Whh2, bih2, bhh2,
                     Wih3, Whh3, bih3, bhh3, Wfc, bfc);
  hipLaunchKernelGGL(lstm_main, dim3(B / 64), dim3(1024), 0, stream, x, out);
}

// Round 4
// 2974.271 us; speedup vs baseline: 1.2535x; 1.2535x over previous
//
#include <hip/hip_runtime.h>

// LSTM_84344567759011: 3-layer LSTM (B=16384, T=200, F=10, H=30) + FC(30->1), fp32.
//
// Round 4: layer-pipelined phases (L1(t=p), L2(t=p-1), L3(t=p-2); one barrier
// per phase, 202 total) -- but layers processed SEQUENTIALLY inside the phase
// with a minimal live set: one z[8] accumulator block at a time, h operands
// loaded from LDS in 15-float chunks consumed immediately. Round 3 kept all
// three layers' accumulators + a shared 30-float h vector live and the
// compiler serviced the overflow with AGPR cross-copies (VALU!) -- 2.2x VALU
// instruction inflation at VGPR_Count=56. This round stays under the cliff.
// Weights stream on the scalar pipe (wave-uniform rows: wave w owns units
// {2w,2w+1}, packed row = w*8 + gate*2 + u). 256 blocks x 1024 threads,
// lane = batch elem, parity ping-pong LDS h buffers (pitch 33: conflict-free).

#define LOG2E 1.44269504088896340736f

static constexpr int B = 16384;
static constexpr int T = 200;
static constexpr int F = 10;
static constexpr int H = 30;

static constexpr int W1_OFF = 0;       // [128][40]
static constexpr int W2_OFF = 5120;    // [128][60]
static constexpr int W3_OFF = 12800;   // [128][60]
static constexpr int B1_OFF = 20480;   // [128]
static constexpr int B2_OFF = 20608;
static constexpr int B3_OFF = 20736;
static constexpr int WFC_OFF = 20864;
static constexpr int BFC_OFF = 20894;

__device__ float g_w[20896];

// packed row pr (0..127): wv = pr>>3, idx = pr&7, gate g = idx>>1, u = idx&1
// source unit j = wv*2+u (valid if j<30), source row sr = g*30 + j.
__global__ void lstm_prep(const float* __restrict__ Wih1, const float* __restrict__ Whh1,
                          const float* __restrict__ bih1, const float* __restrict__ bhh1,
                          const float* __restrict__ Wih2, const float* __restrict__ Whh2,
                          const float* __restrict__ bih2, const float* __restrict__ bhh2,
                          const float* __restrict__ Wih3, const float* __restrict__ Whh3,
                          const float* __restrict__ bih3, const float* __restrict__ bhh3,
                          const float* __restrict__ Wfc, const float* __restrict__ bfc) {
  const int tid = threadIdx.x;  // 256 threads, 1 block
  for (int idx = tid; idx < 128 * 40; idx += 256) {
    int pr = idx / 40, k = idx - pr * 40;
    int wv = pr >> 3, g = (pr >> 1) & 3, u = pr & 1;
    int j = wv * 2 + u;
    float v = 0.f;
    if (j < H) {
      int sr = g * H + j;
      v = (k < F) ? Wih1[sr * F + k] : Whh1[sr * H + (k - F)];
    }
    g_w[W1_OFF + idx] = v;
  }
  for (int idx = tid; idx < 128 * 60; idx += 256) {
    int pr = idx / 60, k = idx - pr * 60;
    int wv = pr >> 3, g = (pr >> 1) & 3, u = pr & 1;
    int j = wv * 2 + u;
    float v2 = 0.f, v3 = 0.f;
    if (j < H) {
      int sr = g * H + j;
      v2 = (k < H) ? Wih2[sr * H + k] : Whh2[sr * H + (k - H)];
      v3 = (k < H) ? Wih3[sr * H + k] : Whh3[sr * H + (k - H)];
    }
    g_w[W2_OFF + idx] = v2;
    g_w[W3_OFF + idx] = v3;
  }
  for (int pr = tid; pr < 128; pr += 256) {
    int wv = pr >> 3, g = (pr >> 1) & 3, u = pr & 1;
    int j = wv * 2 + u;
    float v1 = 0.f, v2 = 0.f, v3 = 0.f;
    if (j < H) {
      int sr = g * H + j;
      v1 = bih1[sr] + bhh1[sr];
      v2 = bih2[sr] + bhh2[sr];
      v3 = bih3[sr] + bhh3[sr];
    }
    g_w[B1_OFF + pr] = v1;
    g_w[B2_OFF + pr] = v2;
    g_w[B3_OFF + pr] = v3;
  }
  if (tid < H) g_w[WFC_OFF + tid] = Wfc[tid];
  if (tid == 0) g_w[BFC_OFF] = bfc[0];
}

__device__ __forceinline__ float sigx(float x) {
  return __builtin_amdgcn_rcpf(1.f + __builtin_amdgcn_exp2f(-x * LOG2E));
}
__device__ __forceinline__ float tanhx(float x) {
  float e = __builtin_amdgcn_exp2f(-x * (2.f * LOG2E));
  return fmaf(2.f, __builtin_amdgcn_rcpf(1.f + e), -1.f);
}

__device__ __forceinline__ void upd(const float* z, float* c, float* hw, int wv) {
#pragma unroll
  for (int u = 0; u < 2; ++u) {
    float ii = sigx(z[u]);
    float ff = sigx(z[2 + u]);
    float gg = tanhx(z[4 + u]);
    float oo = sigx(z[6 + u]);
    float cc = fmaf(ff, c[u], ii * gg);
    c[u] = cc;
    hw[wv * 2 + u] = oo * tanhx(cc);
  }
}

static constexpr int HP = 64 * 33;  // one parity buffer, floats

// Accumulate a 30-long h segment into z[8], in 2 chunks of 15 (small live set).
// woff/K/kbase: weight block, row stride, column base. hr: LDS h vector.
__device__ __forceinline__ void accum_h30(float* z, int rb, int woff, int K, int kbase,
                                          const float* __restrict__ hr) {
#pragma unroll
  for (int cc = 0; cc < 2; ++cc) {
    float hv[15];
#pragma unroll
    for (int k = 0; k < 15; ++k) hv[k] = hr[cc * 15 + k];
#pragma unroll
    for (int r = 0; r < 8; ++r) {
      const float* wr = g_w + woff + (rb + r) * K + kbase + cc * 15;
      float a = z[r];
#pragma unroll
      for (int k = 0; k < 15; ++k) a = fmaf(wr[k], hv[k], a);
      z[r] = a;
    }
  }
}

// Phase p: L1(t=p) if L1A, L2(t=p-1) if L2A, L3(t=p-2) if L3A. All reads from
// parity rp (previous phase's writes), all writes to wp. PF: prefetch x(p+1).
template <bool L1A, bool L2A, bool L3A, bool PF>
__device__ __forceinline__ void do_phase(int p, int b, int wv,
                                         const float* __restrict__ xb,
                                         float* xv,
                                         float* c1, float* c2, float* c3,
                                         float* __restrict__ hs) {
  const int wp = p & 1, rp = wp ^ 1;
  const int rb = wv * 8;

  // ---- L1: z = b1 + W1x.x + W1h.h1(p-1)
  if (L1A) {
    float z[8];
#pragma unroll
    for (int r = 0; r < 8; ++r) z[r] = g_w[B1_OFF + rb + r];
#pragma unroll
    for (int r = 0; r < 8; ++r) {
      const float* wr = g_w + W1_OFF + (rb + r) * 40;
      float a = z[r];
#pragma unroll
      for (int k = 0; k < F; ++k) a = fmaf(wr[k], xv[k], a);
      z[r] = a;
    }
    if (PF) {  // xv dead; reload with x(p+1) -- latency hides under the rest
#pragma unroll
      for (int i = 0; i < 5; ++i) {
        float2 t2 = *(const float2*)(xb + (p + 1) * F + i * 2);
        xv[2 * i] = t2.x;
        xv[2 * i + 1] = t2.y;
      }
    }
    accum_h30(z, rb, W1_OFF, 40, F, hs + (0 * 2 + rp) * HP + b * 33);
    upd(z, c1, hs + (0 * 2 + wp) * HP + b * 33, wv);
  }

  // ---- L2: z = b2 + W2x.h1(p-1) + W2h.h2(p-2)
  if (L2A) {
    float z[8];
#pragma unroll
    for (int r = 0; r < 8; ++r) z[r] = g_w[B2_OFF + rb + r];
    accum_h30(z, rb, W2_OFF, 60, 0, hs + (0 * 2 + rp) * HP + b * 33);
    accum_h30(z, rb, W2_OFF, 60, H, hs + (1 * 2 + rp) * HP + b * 33);
    upd(z, c2, hs + (1 * 2 + wp) * HP + b * 33, wv);
  }

  // ---- L3: z = b3 + W3x.h2(p-2) + W3h.h3(p-3)
  if (L3A) {
    float z[8];
#pragma unroll
    for (int r = 0; r < 8; ++r) z[r] = g_w[B3_OFF + rb + r];
    accum_h30(z, rb, W3_OFF, 60, 0, hs + (1 * 2 + rp) * HP + b * 33);
    accum_h30(z, rb, W3_OFF, 60, H, hs + (2 * 2 + rp) * HP + b * 33);
    upd(z, c3, hs + (2 * 2 + wp) * HP + b * 33, wv);
  }

  __syncthreads();
}

__global__ __launch_bounds__(1024, 4) void lstm_main(const float* __restrict__ x,
                                                     float* __restrict__ out) {
  __shared__ float h_s[3 * 2 * HP];  // [layer][parity][b][33], pitch 33

  const int tid = threadIdx.x;
  const int b = tid & 63;                                   // batch lane
  const int wv = __builtin_amdgcn_readfirstlane(tid >> 6);  // wave 0..15
  const int b0 = blockIdx.x * 64;

  for (int i = tid; i < 3 * 2 * HP; i += 1024) h_s[i] = 0.f;
  float c1[2] = {0.f, 0.f};
  float c2[2] = {0.f, 0.f};
  float c3[2] = {0.f, 0.f};

  const float* xb = x + (size_t)(b0 + b) * (T * F);
  float xv[F];
#pragma unroll
  for (int i = 0; i < 5; ++i) {
    float2 t2 = *(const float2*)(xb + i * 2);
    xv[2 * i] = t2.x;
    xv[2 * i + 1] = t2.y;
  }

  __syncthreads();

  // Phases p=0..201: L1 on p<=199 (t=p), L2 on 1<=p<=200, L3 on 2<=p<=201.
  do_phase<true, false, false, true>(0, b, wv, xb, xv, c1, c2, c3, h_s);
  do_phase<true, true, false, true>(1, b, wv, xb, xv, c1, c2, c3, h_s);
  for (int p = 2; p < 199; ++p)
    do_phase<true, true, true, true>(p, b, wv, xb, xv, c1, c2, c3, h_s);
  do_phase<true, true, true, false>(199, b, wv, xb, xv, c1, c2, c3, h_s);
  do_phase<false, true, true, false>(200, b, wv, xb, xv, c1, c2, c3, h_s);
  do_phase<false, false, true, false>(201, b, wv, xb, xv, c1, c2, c3, h_s);

  // ---- FC epilogue: out[b] = h3(199) . Wfc + bfc. h3(199) written in phase
  // 201, parity 201&1 = 1.
  if (wv == 0) {
    const float* h3 = h_s + (2 * 2 + 1) * HP + b * 33;
    float acc = g_w[BFC_OFF];
#pragma unroll
    for (int k = 0; k < H; ++k) acc = fmaf(h3[k], g_w[WFC_OFF + k], acc);
    out[b0 + b] = acc;
  }
}

extern "C" void kernel_launch(void* const* d_in, const int* in_sizes, int n_in,
                              void* d_out, int out_size, void* d_ws, size_t ws_size,
                              hipStream_t stream) {
  const float* x = (const float*)d_in[0];
  const float* Wih1 = (const float*)d_in[1];
  const float* Whh1 = (const float*)d_in[2];
  const float* bih1 = (const float*)d_in[3];
  const float* bhh1 = (const float*)d_in[4];
  const float* Wih2 = (const float*)d_in[5];
  const float* Whh2 = (const float*)d_in[6];
  const float* bih2 = (const float*)d_in[7];
  const float* bhh2 = (const float*)d_in[8];
  const float* Wih3 = (const float*)d_in[9];
  const float* Whh3 = (const float*)d_in[10];
  const float* bih3 = (const float*)d_in[11];
  const float* bhh3 = (const float*)d_in[12];
  const float* Wfc = (const float*)d_in[13];
  const float* bfc = (const float*)d_in[14];
  float* out = (float*)d_out;

  hipLaunchKernelGGL(lstm_prep, dim3(1), dim3(256), 0, stream,
                     Wih1, Whh1, bih1, bhh1, Wih2, Whh2, bih2, bhh2,
                     Wih3, Whh3, bih3, bhh3, Wfc, bfc);
  hipLaunchKernelGGL(lstm_main, dim3(B / 64), dim3(1024), 0, stream, x, out);
}

// Round 5
// 2094.888 us; speedup vs baseline: 1.7798x; 1.4198x over previous
//
#include <hip/hip_runtime.h>

// LSTM_84344567759011: 3-layer LSTM (B=16384, T=200, F=10, H=30) + FC(30->1), fp32.
//
// Round 5: round-2's phase body VERBATIM (the only structure with proven good
// codegen: hop[K] built up-front, 8 rows x 2 explicit FMA chains, z in regs,
// thread-local update) -- with the single variable change: layer pipelining.
// Phase p computes L1(t=p), L2(t=p-1), L3(t=p-2); all layers read parity rp,
// write parity wp -> ONE barrier per phase (202 total vs round 2's 600).
// Round 3 (fused operands) and round 4 (chunked operands) both showed the
// phase-body rewrite inflated VALU cycles ~1.6-2.2x; this round changes only
// the barrier schedule. Weights stream on the scalar pipe (wave-uniform rows:
// wave w owns units {2w,2w+1}, packed row = w*8 + gate*2 + u).
// 256 blocks x 1024 threads, lane = batch elem; LDS h pitch 33 (conflict-free).

#define LOG2E 1.44269504088896340736f

static constexpr int B = 16384;
static constexpr int T = 200;
static constexpr int F = 10;
static constexpr int H = 30;

static constexpr int W1_OFF = 0;       // [128][40]
static constexpr int W2_OFF = 5120;    // [128][60]
static constexpr int W3_OFF = 12800;   // [128][60]
static constexpr int B1_OFF = 20480;   // [128]
static constexpr int B2_OFF = 20608;
static constexpr int B3_OFF = 20736;
static constexpr int WFC_OFF = 20864;
static constexpr int BFC_OFF = 20894;

__device__ float g_w[20896];

// packed row pr (0..127): wv = pr>>3, idx = pr&7, gate g = idx>>1, u = idx&1
// source unit j = wv*2+u (valid if j<30), source row sr = g*30 + j.
__global__ void lstm_prep(const float* __restrict__ Wih1, const float* __restrict__ Whh1,
                          const float* __restrict__ bih1, const float* __restrict__ bhh1,
                          const float* __restrict__ Wih2, const float* __restrict__ Whh2,
                          const float* __restrict__ bih2, const float* __restrict__ bhh2,
                          const float* __restrict__ Wih3, const float* __restrict__ Whh3,
                          const float* __restrict__ bih3, const float* __restrict__ bhh3,
                          const float* __restrict__ Wfc, const float* __restrict__ bfc) {
  const int tid = threadIdx.x;  // 256 threads, 1 block
  for (int idx = tid; idx < 128 * 40; idx += 256) {
    int pr = idx / 40, k = idx - pr * 40;
    int wv = pr >> 3, g = (pr >> 1) & 3, u = pr & 1;
    int j = wv * 2 + u;
    float v = 0.f;
    if (j < H) {
      int sr = g * H + j;
      v = (k < F) ? Wih1[sr * F + k] : Whh1[sr * H + (k - F)];
    }
    g_w[W1_OFF + idx] = v;
  }
  for (int idx = tid; idx < 128 * 60; idx += 256) {
    int pr = idx / 60, k = idx - pr * 60;
    int wv = pr >> 3, g = (pr >> 1) & 3, u = pr & 1;
    int j = wv * 2 + u;
    float v2 = 0.f, v3 = 0.f;
    if (j < H) {
      int sr = g * H + j;
      v2 = (k < H) ? Wih2[sr * H + k] : Whh2[sr * H + (k - H)];
      v3 = (k < H) ? Wih3[sr * H + k] : Whh3[sr * H + (k - H)];
    }
    g_w[W2_OFF + idx] = v2;
    g_w[W3_OFF + idx] = v3;
  }
  for (int pr = tid; pr < 128; pr += 256) {
    int wv = pr >> 3, g = (pr >> 1) & 3, u = pr & 1;
    int j = wv * 2 + u;
    float v1 = 0.f, v2 = 0.f, v3 = 0.f;
    if (j < H) {
      int sr = g * H + j;
      v1 = bih1[sr] + bhh1[sr];
      v2 = bih2[sr] + bhh2[sr];
      v3 = bih3[sr] + bhh3[sr];
    }
    g_w[B1_OFF + pr] = v1;
    g_w[B2_OFF + pr] = v2;
    g_w[B3_OFF + pr] = v3;
  }
  if (tid < H) g_w[WFC_OFF + tid] = Wfc[tid];
  if (tid == 0) g_w[BFC_OFF] = bfc[0];
}

__device__ __forceinline__ float sigx(float x) {
  return __builtin_amdgcn_rcpf(1.f + __builtin_amdgcn_exp2f(-x * LOG2E));
}
__device__ __forceinline__ float tanhx(float x) {
  float e = __builtin_amdgcn_exp2f(-x * (2.f * LOG2E));
  return fmaf(2.f, __builtin_amdgcn_rcpf(1.f + e), -1.f);
}

// Round-2 phase body, verbatim: GEMM (8 packed rows, z in regs) +
// thread-local gate update. K = 40 (L1: [x|h1]) or 60 ([h_prev|h_own]).
template <int K, bool FIRST>
__device__ __forceinline__ void phase(const float* __restrict__ win,
                                      const float* __restrict__ bin,
                                      const float* xv,
                                      const float* __restrict__ hprev_lds,
                                      const float* __restrict__ hown_lds,
                                      float* __restrict__ hout_lds,
                                      float* c, int wv) {
  float hop[K];
#pragma unroll
  for (int k = 0; k < K - H; ++k) hop[k] = FIRST ? xv[k] : hprev_lds[k];
#pragma unroll
  for (int k = 0; k < H; ++k) hop[K - H + k] = hown_lds[k];

  float z[8];
  const float* wb = win + (wv * 8) * K;  // wave-uniform -> scalar loads
#pragma unroll
  for (int r = 0; r < 8; ++r) {
    const float* wr = wb + r * K;
    float a0 = bin[wv * 8 + r], a1 = 0.f;
#pragma unroll
    for (int k = 0; k < K; k += 2) {
      a0 = fmaf(wr[k], hop[k], a0);
      a1 = fmaf(wr[k + 1], hop[k + 1], a1);
    }
    z[r] = a0 + a1;
  }
#pragma unroll
  for (int u = 0; u < 2; ++u) {
    float ii = sigx(z[u]);
    float ff = sigx(z[2 + u]);
    float gg = tanhx(z[4 + u]);
    float oo = sigx(z[6 + u]);
    float cc = fmaf(ff, c[u], ii * gg);
    c[u] = cc;
    hout_lds[wv * 2 + u] = oo * tanhx(cc);
  }
}

static constexpr int HP = 64 * 33;  // one parity buffer, floats

// Phase p: L1(t=p) if L1A, L2(t=p-1) if L2A, L3(t=p-2) if L3A. All layers
// read parity rp (previous phase's writes), write parity wp -> independent
// within the phase -> single barrier. PF: prefetch x(p+1) after L1 used xv.
template <bool L1A, bool L2A, bool L3A, bool PF>
__device__ __forceinline__ void do_phase(int p, int b, int wv,
                                         const float* __restrict__ xb,
                                         float* xv,
                                         float* c1, float* c2, float* c3,
                                         float* __restrict__ hs) {
  const int wp = p & 1, rp = wp ^ 1;
  float* h1r = hs + (0 * 2 + rp) * HP + b * 33;
  float* h2r = hs + (1 * 2 + rp) * HP + b * 33;
  float* h3r = hs + (2 * 2 + rp) * HP + b * 33;
  float* h1w = hs + (0 * 2 + wp) * HP + b * 33;
  float* h2w = hs + (1 * 2 + wp) * HP + b * 33;
  float* h3w = hs + (2 * 2 + wp) * HP + b * 33;

  if (L1A)
    phase<40, true>(g_w + W1_OFF, g_w + B1_OFF, xv, nullptr, h1r, h1w, c1, wv);
  if (PF) {  // xv dead now; reload with x(p+1), latency hides under L2/L3
#pragma unroll
    for (int i = 0; i < 5; ++i) {
      float2 t2 = *(const float2*)(xb + (p + 1) * F + i * 2);
      xv[2 * i] = t2.x;
      xv[2 * i + 1] = t2.y;
    }
  }
  if (L2A)
    phase<60, false>(g_w + W2_OFF, g_w + B2_OFF, nullptr, h1r, h2r, h2w, c2, wv);
  if (L3A)
    phase<60, false>(g_w + W3_OFF, g_w + B3_OFF, nullptr, h2r, h3r, h3w, c3, wv);

  __syncthreads();
}

__global__ __launch_bounds__(1024, 4) void lstm_main(const float* __restrict__ x,
                                                     float* __restrict__ out) {
  __shared__ float h_s[3 * 2 * HP];  // [layer][parity][b][33], pitch 33

  const int tid = threadIdx.x;
  const int b = tid & 63;                                   // batch lane
  const int wv = __builtin_amdgcn_readfirstlane(tid >> 6);  // wave 0..15
  const int b0 = blockIdx.x * 64;

  for (int i = tid; i < 3 * 2 * HP; i += 1024) h_s[i] = 0.f;
  float c1[2] = {0.f, 0.f};
  float c2[2] = {0.f, 0.f};
  float c3[2] = {0.f, 0.f};

  const float* xb = x + (size_t)(b0 + b) * (T * F);
  float xv[F];
#pragma unroll
  for (int i = 0; i < 5; ++i) {
    float2 t2 = *(const float2*)(xb + i * 2);
    xv[2 * i] = t2.x;
    xv[2 * i + 1] = t2.y;
  }

  __syncthreads();

  // Phases p=0..201: L1 on p<=199 (t=p), L2 on 1<=p<=200, L3 on 2<=p<=201.
  do_phase<true, false, false, true>(0, b, wv, xb, xv, c1, c2, c3, h_s);
  do_phase<true, true, false, true>(1, b, wv, xb, xv, c1, c2, c3, h_s);
  for (int p = 2; p < 199; ++p)
    do_phase<true, true, true, true>(p, b, wv, xb, xv, c1, c2, c3, h_s);
  do_phase<true, true, true, false>(199, b, wv, xb, xv, c1, c2, c3, h_s);
  do_phase<false, true, true, false>(200, b, wv, xb, xv, c1, c2, c3, h_s);
  do_phase<false, false, true, false>(201, b, wv, xb, xv, c1, c2, c3, h_s);

  // ---- FC epilogue: out[b] = h3(199) . Wfc + bfc. h3(199) written in phase
  // 201, parity 201&1 = 1.
  if (wv == 0) {
    const float* h3 = h_s + (2 * 2 + 1) * HP + b * 33;
    float acc = g_w[BFC_OFF];
#pragma unroll
    for (int k = 0; k < H; ++k) acc = fmaf(h3[k], g_w[WFC_OFF + k], acc);
    out[b0 + b] = acc;
  }
}

extern "C" void kernel_launch(void* const* d_in, const int* in_sizes, int n_in,
                              void* d_out, int out_size, void* d_ws, size_t ws_size,
                              hipStream_t stream) {
  const float* x = (const float*)d_in[0];
  const float* Wih1 = (const float*)d_in[1];
  const float* Whh1 = (const float*)d_in[2];
  const float* bih1 = (const float*)d_in[3];
  const float* bhh1 = (const float*)d_in[4];
  const float* Wih2 = (const float*)d_in[5];
  const float* Whh2 = (const float*)d_in[6];
  const float* bih2 = (const float*)d_in[7];
  const float* bhh2 = (const float*)d_in[8];
  const float* Wih3 = (const float*)d_in[9];
  const float* Whh3 = (const float*)d_in[10];
  const float* bih3 = (const float*)d_in[11];
  const float* bhh3 = (const float*)d_in[12];
  const float* Wfc = (const float*)d_in[13];
  const float* bfc = (const float*)d_in[14];
  float* out = (float*)d_out;

  hipLaunchKernelGGL(lstm_prep, dim3(1), dim3(256), 0, stream,
                     Wih1, Whh1, bih1, bhh1, Wih2, Whh2, bih2, bhh2,
                     Wih3, Whh3, bih3, bhh3, Wfc, bfc);
  hipLaunchKernelGGL(lstm_main, dim3(B / 64), dim3(1024), 0, stream, x, out);
}

// Round 6
// 2089.726 us; speedup vs baseline: 1.7842x; 1.0025x over previous
//
#include <hip/hip_runtime.h>

// LSTM_84344567759011: 3-layer LSTM (B=16384, T=200, F=10, H=30) + FC(30->1), fp32.
//
// Round 6: round 5 verbatim EXCEPT __launch_bounds__(1024) without the
// min-waves arg. Round 5's (1024,4) made the allocator pick a 64-VGPR tier
// and spill the hop/xv/c overflow to scratch (WRITE_SIZE 64KB -> 2112KB) --
// scratch latency in every phase explains r5 > r2 despite 3x fewer barriers
// and lower instruction count. A 1024-thread block hardware-caps VGPR at 128
// anyway (16 waves/CU must co-reside), so dropping the hint cannot reduce
// occupancy; it only allows ~100 arch VGPRs -> no spill.
// Structure: layer-pipelined phases (L1(t=p), L2(t=p-1), L3(t=p-2)), one
// barrier per phase (202 total), round-2 phase body (hop[K] up-front, 8 rows
// x 2 FMA chains, z in regs, thread-local update). Weights stream on the
// scalar pipe (wave-uniform rows: wave w owns units {2w,2w+1}). 256 blocks x
// 1024 threads, lane = batch elem; LDS h pitch 33 (conflict-free).

#define LOG2E 1.44269504088896340736f

static constexpr int B = 16384;
static constexpr int T = 200;
static constexpr int F = 10;
static constexpr int H = 30;

static constexpr int W1_OFF = 0;       // [128][40]
static constexpr int W2_OFF = 5120;    // [128][60]
static constexpr int W3_OFF = 12800;   // [128][60]
static constexpr int B1_OFF = 20480;   // [128]
static constexpr int B2_OFF = 20608;
static constexpr int B3_OFF = 20736;
static constexpr int WFC_OFF = 20864;
static constexpr int BFC_OFF = 20894;

__device__ float g_w[20896];

// packed row pr (0..127): wv = pr>>3, idx = pr&7, gate g = idx>>1, u = idx&1
// source unit j = wv*2+u (valid if j<30), source row sr = g*30 + j.
__global__ void lstm_prep(const float* __restrict__ Wih1, const float* __restrict__ Whh1,
                          const float* __restrict__ bih1, const float* __restrict__ bhh1,
                          const float* __restrict__ Wih2, const float* __restrict__ Whh2,
                          const float* __restrict__ bih2, const float* __restrict__ bhh2,
                          const float* __restrict__ Wih3, const float* __restrict__ Whh3,
                          const float* __restrict__ bih3, const float* __restrict__ bhh3,
                          const float* __restrict__ Wfc, const float* __restrict__ bfc) {
  const int tid = threadIdx.x;  // 256 threads, 1 block
  for (int idx = tid; idx < 128 * 40; idx += 256) {
    int pr = idx / 40, k = idx - pr * 40;
    int wv = pr >> 3, g = (pr >> 1) & 3, u = pr & 1;
    int j = wv * 2 + u;
    float v = 0.f;
    if (j < H) {
      int sr = g * H + j;
      v = (k < F) ? Wih1[sr * F + k] : Whh1[sr * H + (k - F)];
    }
    g_w[W1_OFF + idx] = v;
  }
  for (int idx = tid; idx < 128 * 60; idx += 256) {
    int pr = idx / 60, k = idx - pr * 60;
    int wv = pr >> 3, g = (pr >> 1) & 3, u = pr & 1;
    int j = wv * 2 + u;
    float v2 = 0.f, v3 = 0.f;
    if (j < H) {
      int sr = g * H + j;
      v2 = (k < H) ? Wih2[sr * H + k] : Whh2[sr * H + (k - H)];
      v3 = (k < H) ? Wih3[sr * H + k] : Whh3[sr * H + (k - H)];
    }
    g_w[W2_OFF + idx] = v2;
    g_w[W3_OFF + idx] = v3;
  }
  for (int pr = tid; pr < 128; pr += 256) {
    int wv = pr >> 3, g = (pr >> 1) & 3, u = pr & 1;
    int j = wv * 2 + u;
    float v1 = 0.f, v2 = 0.f, v3 = 0.f;
    if (j < H) {
      int sr = g * H + j;
      v1 = bih1[sr] + bhh1[sr];
      v2 = bih2[sr] + bhh2[sr];
      v3 = bih3[sr] + bhh3[sr];
    }
    g_w[B1_OFF + pr] = v1;
    g_w[B2_OFF + pr] = v2;
    g_w[B3_OFF + pr] = v3;
  }
  if (tid < H) g_w[WFC_OFF + tid] = Wfc[tid];
  if (tid == 0) g_w[BFC_OFF] = bfc[0];
}

__device__ __forceinline__ float sigx(float x) {
  return __builtin_amdgcn_rcpf(1.f + __builtin_amdgcn_exp2f(-x * LOG2E));
}
__device__ __forceinline__ float tanhx(float x) {
  float e = __builtin_amdgcn_exp2f(-x * (2.f * LOG2E));
  return fmaf(2.f, __builtin_amdgcn_rcpf(1.f + e), -1.f);
}

// Round-2 phase body, verbatim: GEMM (8 packed rows, z in regs) +
// thread-local gate update. K = 40 (L1: [x|h1]) or 60 ([h_prev|h_own]).
template <int K, bool FIRST>
__device__ __forceinline__ void phase(const float* __restrict__ win,
                                      const float* __restrict__ bin,
                                      const float* xv,
                                      const float* __restrict__ hprev_lds,
                                      const float* __restrict__ hown_lds,
                                      float* __restrict__ hout_lds,
                                      float* c, int wv) {
  float hop[K];
#pragma unroll
  for (int k = 0; k < K - H; ++k) hop[k] = FIRST ? xv[k] : hprev_lds[k];
#pragma unroll
  for (int k = 0; k < H; ++k) hop[K - H + k] = hown_lds[k];

  float z[8];
  const float* wb = win + (wv * 8) * K;  // wave-uniform -> scalar loads
#pragma unroll
  for (int r = 0; r < 8; ++r) {
    const float* wr = wb + r * K;
    float a0 = bin[wv * 8 + r], a1 = 0.f;
#pragma unroll
    for (int k = 0; k < K; k += 2) {
      a0 = fmaf(wr[k], hop[k], a0);
      a1 = fmaf(wr[k + 1], hop[k + 1], a1);
    }
    z[r] = a0 + a1;
  }
#pragma unroll
  for (int u = 0; u < 2; ++u) {
    float ii = sigx(z[u]);
    float ff = sigx(z[2 + u]);
    float gg = tanhx(z[4 + u]);
    float oo = sigx(z[6 + u]);
    float cc = fmaf(ff, c[u], ii * gg);
    c[u] = cc;
    hout_lds[wv * 2 + u] = oo * tanhx(cc);
  }
}

static constexpr int HP = 64 * 33;  // one parity buffer, floats

// Phase p: L1(t=p) if L1A, L2(t=p-1) if L2A, L3(t=p-2) if L3A. All layers
// read parity rp (previous phase's writes), write parity wp -> independent
// within the phase -> single barrier. PF: prefetch x(p+1) after L1 used xv.
template <bool L1A, bool L2A, bool L3A, bool PF>
__device__ __forceinline__ void do_phase(int p, int b, int wv,
                                         const float* __restrict__ xb,
                                         float* xv,
                                         float* c1, float* c2, float* c3,
                                         float* __restrict__ hs) {
  const int wp = p & 1, rp = wp ^ 1;
  float* h1r = hs + (0 * 2 + rp) * HP + b * 33;
  float* h2r = hs + (1 * 2 + rp) * HP + b * 33;
  float* h3r = hs + (2 * 2 + rp) * HP + b * 33;
  float* h1w = hs + (0 * 2 + wp) * HP + b * 33;
  float* h2w = hs + (1 * 2 + wp) * HP + b * 33;
  float* h3w = hs + (2 * 2 + wp) * HP + b * 33;

  if (L1A)
    phase<40, true>(g_w + W1_OFF, g_w + B1_OFF, xv, nullptr, h1r, h1w, c1, wv);
  if (PF) {  // xv dead now; reload with x(p+1), latency hides under L2/L3
#pragma unroll
    for (int i = 0; i < 5; ++i) {
      float2 t2 = *(const float2*)(xb + (p + 1) * F + i * 2);
      xv[2 * i] = t2.x;
      xv[2 * i + 1] = t2.y;
    }
  }
  if (L2A)
    phase<60, false>(g_w + W2_OFF, g_w + B2_OFF, nullptr, h1r, h2r, h2w, c2, wv);
  if (L3A)
    phase<60, false>(g_w + W3_OFF, g_w + B3_OFF, nullptr, h2r, h3r, h3w, c3, wv);

  __syncthreads();
}

__global__ __launch_bounds__(1024) void lstm_main(const float* __restrict__ x,
                                                  float* __restrict__ out) {
  __shared__ float h_s[3 * 2 * HP];  // [layer][parity][b][33], pitch 33

  const int tid = threadIdx.x;
  const int b = tid & 63;                                   // batch lane
  const int wv = __builtin_amdgcn_readfirstlane(tid >> 6);  // wave 0..15
  const int b0 = blockIdx.x * 64;

  for (int i = tid; i < 3 * 2 * HP; i += 1024) h_s[i] = 0.f;
  float c1[2] = {0.f, 0.f};
  float c2[2] = {0.f, 0.f};
  float c3[2] = {0.f, 0.f};

  const float* xb = x + (size_t)(b0 + b) * (T * F);
  float xv[F];
#pragma unroll
  for (int i = 0; i < 5; ++i) {
    float2 t2 = *(const float2*)(xb + i * 2);
    xv[2 * i] = t2.x;
    xv[2 * i + 1] = t2.y;
  }

  __syncthreads();

  // Phases p=0..201: L1 on p<=199 (t=p), L2 on 1<=p<=200, L3 on 2<=p<=201.
  do_phase<true, false, false, true>(0, b, wv, xb, xv, c1, c2, c3, h_s);
  do_phase<true, true, false, true>(1, b, wv, xb, xv, c1, c2, c3, h_s);
  for (int p = 2; p < 199; ++p)
    do_phase<true, true, true, true>(p, b, wv, xb, xv, c1, c2, c3, h_s);
  do_phase<true, true, true, false>(199, b, wv, xb, xv, c1, c2, c3, h_s);
  do_phase<false, true, true, false>(200, b, wv, xb, xv, c1, c2, c3, h_s);
  do_phase<false, false, true, false>(201, b, wv, xb, xv, c1, c2, c3, h_s);

  // ---- FC epilogue: out[b] = h3(199) . Wfc + bfc. h3(199) written in phase
  // 201, parity 201&1 = 1.
  if (wv == 0) {
    const float* h3 = h_s + (2 * 2 + 1) * HP + b * 33;
    float acc = g_w[BFC_OFF];
#pragma unroll
    for (int k = 0; k < H; ++k) acc = fmaf(h3[k], g_w[WFC_OFF + k], acc);
    out[b0 + b] = acc;
  }
}

extern "C" void kernel_launch(void* const* d_in, const int* in_sizes, int n_in,
                              void* d_out, int out_size, void* d_ws, size_t ws_size,
                              hipStream_t stream) {
  const float* x = (const float*)d_in[0];
  const float* Wih1 = (const float*)d_in[1];
  const float* Whh1 = (const float*)d_in[2];
  const float* bih1 = (const float*)d_in[3];
  const float* bhh1 = (const float*)d_in[4];
  const float* Wih2 = (const float*)d_in[5];
  const float* Whh2 = (const float*)d_in[6];
  const float* bih2 = (const float*)d_in[7];
  const float* bhh2 = (const float*)d_in[8];
  const float* Wih3 = (const float*)d_in[9];
  const float* Whh3 = (const float*)d_in[10];
  const float* bih3 = (const float*)d_in[11];
  const float* bhh3 = (const float*)d_in[12];
  const float* Wfc = (const float*)d_in[13];
  const float* bfc = (const float*)d_in[14];
  float* out = (float*)d_out;

  hipLaunchKernelGGL(lstm_prep, dim3(1), dim3(256), 0, stream,
                     Wih1, Whh1, bih1, bhh1, Wih2, Whh2, bih2, bhh2,
                     Wih3, Whh3, bih3, bhh3, Wfc, bfc);
  hipLaunchKernelGGL(lstm_main, dim3(B / 64), dim3(1024), 0, stream, x, out);
}

// Round 7
// 719.933 us; speedup vs baseline: 5.1788x; 2.9027x over previous
//
#include <hip/hip_runtime.h>

// LSTM_84344567759011: 3-layer LSTM (B=16384, T=200, F=10, H=30) + FC(30->1), fp32.
//
// Round 7: MFMA rewrite. The per-phase op is [128 gates x K<=64] x [K x 32
// batch] — matmul-shaped. fp32 -> fp16 hi/lo split; z = Whi·Hhi + Whi·Hlo +
// Wlo·Hhi via 3 chained v_mfma_f32_32x32x16_f16 per K-slice (err ~1e-5 << 2.3e-3).
// 512 blocks x 256 threads (4 waves = 4 M-tiles), 32 batch/block, 2 blocks/CU
// (barrier overlap). Unified per-parity LDS B-buffer [k][b] f16-pair words,
// k = [x(10)|h1(30)|h2(30)|h3(30)]: h1 written once feeds L1-recurrent AND
// L2-input (window aliasing; A zero-pads make junk-window reads harmless).
// Weights pre-packed in fragment order: packed row = u' + 8g + 4hi matches the
// C layout row=(reg&3)+8(reg>>2)+4(lane>>5), so each lane's 16 C regs = its
// 4 units x 4 gates -> thread-local gate update, c-state in regs.
// Layer-pipelined phases (L1(p), L2(p-1), L3(p-2)), one barrier per phase.

#define LOG2E 1.44269504088896340736f

typedef _Float16 f16x8 __attribute__((ext_vector_type(8)));
typedef float f32x16 __attribute__((ext_vector_type(16)));

static constexpr int B = 16384;
static constexpr int T = 200;
static constexpr int F = 10;
static constexpr int H = 30;

// A-pack: per layer, u32 index = base + ((s*4 + mtile)*2 + chain)*256 + lane*4 + r
// chain 0 = hi, 1 = lo. L1: 3 slices (K pad 48); L2/L3: 4 slices (K pad 64).
static constexpr int A1_OFF = 0;      // 3*4*2*256 = 6144
static constexpr int A2_OFF = 6144;   // 8192
static constexpr int A3_OFF = 14336;  // 8192
__device__ unsigned int g_apack[22528];
__device__ float g_bias[384];  // [layer][mtile*32 + g*8 + lh*4 + u]
__device__ float g_wfc[31];    // [0..29] Wfc, [30] bfc

__device__ __forceinline__ void split16(float w, unsigned short& h, unsigned short& l) {
  _Float16 h16 = (_Float16)w;
  _Float16 l16 = (_Float16)(w - (float)h16);
  h = __builtin_bit_cast(unsigned short, h16);
  l = __builtin_bit_cast(unsigned short, l16);
}

// Pack one layer's weights into fragment order.
// A-frag layout assumed (32x32x16_f16): lane holds A row (lane&31),
// k = (lane>>5)*8 + 2r + e. Packed row rl = u' + 4*lh + 8*g, unit j = m*8+lh*4+u'.
#define PREP_LAYER(BASE, NS, FETCH)                                        \
  for (int idx = tid; idx < (NS)*4*64*4; idx += 256) {                     \
    int r = idx & 3, lane = (idx >> 2) & 63, m = (idx >> 8) & 3,           \
        s = idx >> 10;                                                     \
    int rl = lane & 31, kh = lane >> 5;                                    \
    int u = rl & 3, lh = (rl >> 2) & 1, g = rl >> 3;                       \
    int j = m * 8 + lh * 4 + u;                                            \
    unsigned int whi = 0, wlo = 0;                                         \
    for (int e = 0; e < 2; ++e) {                                          \
      int k = s * 16 + kh * 8 + r * 2 + e;                                 \
      float w = 0.f;                                                       \
      if (j < H) {                                                         \
        int row = g * H + j;                                               \
        w = FETCH;                                                         \
      }                                                                    \
      unsigned short hh, ll;                                               \
      split16(w, hh, ll);                                                  \
      whi |= (unsigned int)hh << (16 * e);                                 \
      wlo |= (unsigned int)ll << (16 * e);                                 \
    }                                                                      \
    int p0 = ((s * 4 + m) * 2) * 256 + lane * 4 + r;                       \
    g_apack[(BASE) + p0] = whi;                                            \
    g_apack[(BASE) + p0 + 256] = wlo;                                      \
  }

__global__ void lstm_prep(const float* __restrict__ Wih1, const float* __restrict__ Whh1,
                          const float* __restrict__ bih1, const float* __restrict__ bhh1,
                          const float* __restrict__ Wih2, const float* __restrict__ Whh2,
                          const float* __restrict__ bih2, const float* __restrict__ bhh2,
                          const float* __restrict__ Wih3, const float* __restrict__ Whh3,
                          const float* __restrict__ bih3, const float* __restrict__ bhh3,
                          const float* __restrict__ Wfc, const float* __restrict__ bfc) {
  const int tid = threadIdx.x;  // 256 threads, 1 block
  PREP_LAYER(A1_OFF, 3,
             (k < F ? Wih1[row * F + k] : (k < F + H ? Whh1[row * H + (k - F)] : 0.f)))
  PREP_LAYER(A2_OFF, 4,
             (k < H ? Wih2[row * H + k] : (k < 2 * H ? Whh2[row * H + (k - H)] : 0.f)))
  PREP_LAYER(A3_OFF, 4,
             (k < H ? Wih3[row * H + k] : (k < 2 * H ? Whh3[row * H + (k - H)] : 0.f)))
  for (int pr = tid; pr < 384; pr += 256) {
    int L = pr >> 7, rr = pr & 127;
    int m = rr >> 5, rl = rr & 31;
    int u = rl & 3, lh = (rl >> 2) & 1, g = rl >> 3;
    int j = m * 8 + lh * 4 + u;
    float v = 0.f;
    if (j < H) {
      int row = g * H + j;
      v = (L == 0) ? bih1[row] + bhh1[row]
                   : (L == 1) ? bih2[row] + bhh2[row] : bih3[row] + bhh3[row];
    }
    g_bias[pr] = v;
  }
  if (tid < H) g_wfc[tid] = Wfc[tid];
  if (tid == 0) g_wfc[30] = bfc[0];
}

__device__ __forceinline__ float sigx(float x) {
  return __builtin_amdgcn_rcpf(1.f + __builtin_amdgcn_exp2f(-x * LOG2E));
}
__device__ __forceinline__ float tanhx(float x) {
  float e = __builtin_amdgcn_exp2f(-x * (2.f * LOG2E));
  return fmaf(2.f, __builtin_amdgcn_rcpf(1.f + e), -1.f);
}
__device__ __forceinline__ unsigned int pack2(float a, float b,
                                              unsigned int& lo_out) {
  unsigned short ah, al, bh2, bl2;
  split16(a, ah, al);
  split16(b, bh2, bl2);
  lo_out = (unsigned int)al | ((unsigned int)bl2 << 16);
  return (unsigned int)ah | ((unsigned int)bh2 << 16);
}

// B k-map (global): 0..9 x | 10..39 h1 | 40..69 h2 | 70..99 h3 | 100..103 zero pad.
// L1 window k 0..47 (koff2=0, 3 slices); L2 k 10..73 (koff2=5, 4 slices);
// L3 k 40..103 (koff2=20, 4 slices).
__global__ __launch_bounds__(256, 2) void lstm_main(const float* __restrict__ x,
                                                    float* __restrict__ out) {
  __shared__ unsigned int bh[2][52][32];  // hi f16 pairs [parity][k>>1][b]
  __shared__ unsigned int bl[2][52][32];  // lo f16 pairs
  __shared__ float bias_s[384];

  const int tid = threadIdx.x;
  const int lane = tid & 63;
  const int wv = __builtin_amdgcn_readfirstlane(tid >> 6);  // mtile 0..3
  const int b32 = lane & 31;
  const int lh = lane >> 5;
  const int boff = lh * 4 * 32 + b32;  // frag word base: [(koff2+s*8+lh*4+w)][b32]
  const int b0 = blockIdx.x * 32;

  unsigned int* bhf = &bh[0][0][0];
  unsigned int* blf = &bl[0][0][0];
  for (int i = tid; i < 2 * 52 * 32; i += 256) { bhf[i] = 0u; blf[i] = 0u; }
  for (int i = tid; i < 384; i += 256) bias_s[i] = g_bias[i];

  // ---- A fragments (persistent in regs; hi & lo chains)
  f16x8 A1h[3], A1l[3], A2h[4], A2l[4], A3h[4], A3l[4];
#pragma unroll
  for (int s = 0; s < 3; ++s) {
    A1h[s] = __builtin_bit_cast(f16x8, *(const uint4*)&g_apack[A1_OFF + ((s * 4 + wv) * 2 + 0) * 256 + lane * 4]);
    A1l[s] = __builtin_bit_cast(f16x8, *(const uint4*)&g_apack[A1_OFF + ((s * 4 + wv) * 2 + 1) * 256 + lane * 4]);
  }
#pragma unroll
  for (int s = 0; s < 4; ++s) {
    A2h[s] = __builtin_bit_cast(f16x8, *(const uint4*)&g_apack[A2_OFF + ((s * 4 + wv) * 2 + 0) * 256 + lane * 4]);
    A2l[s] = __builtin_bit_cast(f16x8, *(const uint4*)&g_apack[A2_OFF + ((s * 4 + wv) * 2 + 1) * 256 + lane * 4]);
    A3h[s] = __builtin_bit_cast(f16x8, *(const uint4*)&g_apack[A3_OFF + ((s * 4 + wv) * 2 + 0) * 256 + lane * 4]);
    A3l[s] = __builtin_bit_cast(f16x8, *(const uint4*)&g_apack[A3_OFF + ((s * 4 + wv) * 2 + 1) * 256 + lane * 4]);
  }

  float c1[4] = {0.f, 0.f, 0.f, 0.f};
  float c2[4] = {0.f, 0.f, 0.f, 0.f};
  float c3[4] = {0.f, 0.f, 0.f, 0.f};

  __syncthreads();  // LDS zeroed before x(0) staging (overlapping region)

  // stage x(0) into parity 1 (phase 0 reads rp=1)
  if (tid < 160) {
    int k2 = tid >> 5, bb = tid & 31;
    const float* xp = x + (size_t)(b0 + bb) * (T * F) + k2 * 2;
    unsigned int wl, wh = pack2(xp[0], xp[1], wl);
    bh[1][k2][bb] = wh;
    bl[1][k2][bb] = wl;
  }
  __syncthreads();

#define GEMM_L(Z, AH, AL, NS, KOFF2)                                  \
  _Pragma("unroll") for (int s = 0; s < (NS); ++s) {                  \
    int i0 = ((KOFF2) + s * 8) * 32 + boff;                           \
    uint4 uh = {BH[i0], BH[i0 + 32], BH[i0 + 64], BH[i0 + 96]};       \
    uint4 ul = {BL[i0], BL[i0 + 32], BL[i0 + 64], BL[i0 + 96]};       \
    f16x8 fbh = __builtin_bit_cast(f16x8, uh);                        \
    f16x8 fbl = __builtin_bit_cast(f16x8, ul);                        \
    Z = __builtin_amdgcn_mfma_f32_32x32x16_f16(AL[s], fbh, Z, 0, 0, 0); \
    Z = __builtin_amdgcn_mfma_f32_32x32x16_f16(AH[s], fbl, Z, 0, 0, 0); \
    Z = __builtin_amdgcn_mfma_f32_32x32x16_f16(AH[s], fbh, Z, 0, 0, 0); \
  }

// lane's C regs: reg = 4g + u' -> row u' + 8g + 4lh; unit j = wv*8 + lh*4 + u'.
#define UPD_L(Z, C, LI, KOFF)                                         \
  _Pragma("unroll") for (int up = 0; up < 4; ++up) {                  \
    int j = wv * 8 + lh * 4 + up;                                     \
    if (j < H) {                                                      \
      int bb = (LI) * 128 + wv * 32 + lh * 4 + up;                    \
      float zi = Z[up] + bias_s[bb];                                  \
      float zf = Z[4 + up] + bias_s[bb + 8];                          \
      float zg = Z[8 + up] + bias_s[bb + 16];                         \
      float zo = Z[12 + up] + bias_s[bb + 24];                        \
      float ii = sigx(zi), ff = sigx(zf);                             \
      float gg = tanhx(zg), oo = sigx(zo);                            \
      float cc = fmaf(ff, C[up], ii * gg);                            \
      C[up] = cc;                                                     \
      float hv = oo * tanhx(cc);                                      \
      _Float16 h16 = (_Float16)hv;                                    \
      _Float16 l16 = (_Float16)(hv - (float)h16);                     \
      int k = (KOFF) + j;                                             \
      int widx = ((k >> 1) * 32 + b32) * 2 + (k & 1);                 \
      BHW[widx] = h16;                                                \
      BLW[widx] = l16;                                                \
    }                                                                 \
  }

  for (int p = 0; p < 202; ++p) {
    const bool L1A = p <= 199;
    const bool L2A = (p >= 1) & (p <= 200);
    const bool L3A = p >= 2;
    const bool PFA = p <= 198;
    const int wp = p & 1, rp = wp ^ 1;
    const unsigned int* BH = &bh[rp][0][0];
    const unsigned int* BL = &bl[rp][0][0];

    // T14 split: issue x(p+1) loads now, write to LDS after compute.
    float xs0 = 0.f, xs1 = 0.f;
    if (PFA & (tid < 160)) {
      const float* xp = x + (size_t)(b0 + (tid & 31)) * (T * F) + (p + 1) * F + (tid >> 5) * 2;
      xs0 = xp[0];
      xs1 = xp[1];
    }

    f32x16 z1 = {}, z2 = {}, z3 = {};
    if (L1A) { GEMM_L(z1, A1h, A1l, 3, 0) }
    if (L2A) { GEMM_L(z2, A2h, A2l, 4, 5) }
    if (L3A) { GEMM_L(z3, A3h, A3l, 4, 20) }

    _Float16* BHW = (_Float16*)&bh[wp][0][0];
    _Float16* BLW = (_Float16*)&bl[wp][0][0];
    if (L1A) { UPD_L(z1, c1, 0, F) }     // h1 -> k 10..39
    if (L2A) { UPD_L(z2, c2, 1, 40) }    // h2 -> k 40..69
    if (L3A) { UPD_L(z3, c3, 2, 70) }    // h3 -> k 70..99

    if (PFA & (tid < 160)) {
      unsigned int wl, wh = pack2(xs0, xs1, wl);
      bh[wp][tid >> 5][tid & 31] = wh;
      bl[wp][tid >> 5][tid & 31] = wl;
    }
    __syncthreads();
  }

  // ---- FC epilogue: h3(199) written at phase 201 -> parity 1.
  if (tid < 32) {
    const _Float16* H3h = (const _Float16*)&bh[1][0][0];
    const _Float16* H3l = (const _Float16*)&bl[1][0][0];
    float acc = g_wfc[30];
#pragma unroll
    for (int j = 0; j < H; ++j) {
      int k = 70 + j;
      int widx = ((k >> 1) * 32 + tid) * 2 + (k & 1);
      float hv = (float)H3h[widx] + (float)H3l[widx];
      acc = fmaf(hv, g_wfc[j], acc);
    }
    out[b0 + tid] = acc;
  }
}

extern "C" void kernel_launch(void* const* d_in, const int* in_sizes, int n_in,
                              void* d_out, int out_size, void* d_ws, size_t ws_size,
                              hipStream_t stream) {
  const float* x = (const float*)d_in[0];
  const float* Wih1 = (const float*)d_in[1];
  const float* Whh1 = (const float*)d_in[2];
  const float* bih1 = (const float*)d_in[3];
  const float* bhh1 = (const float*)d_in[4];
  const float* Wih2 = (const float*)d_in[5];
  const float* Whh2 = (const float*)d_in[6];
  const float* bih2 = (const float*)d_in[7];
  const float* bhh2 = (const float*)d_in[8];
  const float* Wih3 = (const float*)d_in[9];
  const float* Whh3 = (const float*)d_in[10];
  const float* bih3 = (const float*)d_in[11];
  const float* bhh3 = (const float*)d_in[12];
  const float* Wfc = (const float*)d_in[13];
  const float* bfc = (const float*)d_in[14];
  float* out = (float*)d_out;

  hipLaunchKernelGGL(lstm_prep, dim3(1), dim3(256), 0, stream,
                     Wih1, Whh1, bih1, bhh1, Wih2, Whh2, bih2, bhh2,
                     Wih3, Whh3, bih3, bhh3, Wfc, bfc);
  hipLaunchKernelGGL(lstm_main, dim3(B / 32), dim3(256), 0, stream, x, out);
}

// Round 8
// 580.201 us; speedup vs baseline: 6.4260x; 1.2408x over previous
//
#include <hip/hip_runtime.h>

// LSTM_84344567759011: 3-layer LSTM (B=16384, T=200, F=10, H=30) + FC(30->1), fp32.
//
// Round 8: r7's MFMA structure (proven layouts/precision) with VALU-count and
// AGPR-churn fixes:
//  - per-layer GEMM -> UPD (one z f32x16 live at a time -> stays in VGPRs)
//  - bias preloaded into 3 persistent f32x16 regs, used as MFMA C-seed
//    (kills 48 z-init movs + 12 bias LDS reads + 12 adds per phase)
//  - h-writes packed: 12 ds_write_b32 (hi+lo word per unit-pair) vs 24 b16,
//    compile-time LDS offsets
//  - templated head/steady/tail phases (no runtime layer guards)
// Everything else identical to r7: fp32->f16 hi/lo 3-term MFMA chains
// (err ~1e-5), unified B-buffer [k2][32] (bank-conflict-free, verified 0),
// layer-pipelined phases L1(p),L2(p-1),L3(p-2), one barrier/phase, T14 x split.

#define LOG2E 1.44269504088896340736f

typedef _Float16 f16x8 __attribute__((ext_vector_type(8)));
typedef float f32x16 __attribute__((ext_vector_type(16)));

static constexpr int B = 16384;
static constexpr int T = 200;
static constexpr int F = 10;
static constexpr int H = 30;

static constexpr int A1_OFF = 0;      // 3 slices
static constexpr int A2_OFF = 6144;   // 4 slices
static constexpr int A3_OFF = 14336;  // 4 slices
__device__ unsigned int g_apack[22528];
__device__ float g_bias[384];  // [layer][mtile*32 + u + 4*lh + 8*g]
__device__ float g_wfc[31];

__device__ __forceinline__ void split16(float w, unsigned short& h, unsigned short& l) {
  _Float16 h16 = (_Float16)w;
  _Float16 l16 = (_Float16)(w - (float)h16);
  h = __builtin_bit_cast(unsigned short, h16);
  l = __builtin_bit_cast(unsigned short, l16);
}

#define PREP_LAYER(BASE, NS, FETCH)                                        \
  for (int idx = tid; idx < (NS)*4*64*4; idx += 256) {                     \
    int r = idx & 3, lane = (idx >> 2) & 63, m = (idx >> 8) & 3,           \
        s = idx >> 10;                                                     \
    int rl = lane & 31, kh = lane >> 5;                                    \
    int u = rl & 3, lh = (rl >> 2) & 1, g = rl >> 3;                       \
    int j = m * 8 + lh * 4 + u;                                            \
    unsigned int whi = 0, wlo = 0;                                         \
    for (int e = 0; e < 2; ++e) {                                          \
      int k = s * 16 + kh * 8 + r * 2 + e;                                 \
      float w = 0.f;                                                       \
      if (j < H) {                                                         \
        int row = g * H + j;                                               \
        w = FETCH;                                                         \
      }                                                                    \
      unsigned short hh, ll;                                               \
      split16(w, hh, ll);                                                  \
      whi |= (unsigned int)hh << (16 * e);                                 \
      wlo |= (unsigned int)ll << (16 * e);                                 \
    }                                                                      \
    int p0 = ((s * 4 + m) * 2) * 256 + lane * 4 + r;                       \
    g_apack[(BASE) + p0] = whi;                                            \
    g_apack[(BASE) + p0 + 256] = wlo;                                      \
  }

__global__ void lstm_prep(const float* __restrict__ Wih1, const float* __restrict__ Whh1,
                          const float* __restrict__ bih1, const float* __restrict__ bhh1,
                          const float* __restrict__ Wih2, const float* __restrict__ Whh2,
                          const float* __restrict__ bih2, const float* __restrict__ bhh2,
                          const float* __restrict__ Wih3, const float* __restrict__ Whh3,
                          const float* __restrict__ bih3, const float* __restrict__ bhh3,
                          const float* __restrict__ Wfc, const float* __restrict__ bfc) {
  const int tid = threadIdx.x;  // 256 threads, 1 block
  PREP_LAYER(A1_OFF, 3,
             (k < F ? Wih1[row * F + k] : (k < F + H ? Whh1[row * H + (k - F)] : 0.f)))
  PREP_LAYER(A2_OFF, 4,
             (k < H ? Wih2[row * H + k] : (k < 2 * H ? Whh2[row * H + (k - H)] : 0.f)))
  PREP_LAYER(A3_OFF, 4,
             (k < H ? Wih3[row * H + k] : (k < 2 * H ? Whh3[row * H + (k - H)] : 0.f)))
  for (int pr = tid; pr < 384; pr += 256) {
    int L = pr >> 7, rr = pr & 127;
    int m = rr >> 5, rl = rr & 31;
    int u = rl & 3, lh = (rl >> 2) & 1, g = rl >> 3;
    int j = m * 8 + lh * 4 + u;
    float v = 0.f;
    if (j < H) {
      int row = g * H + j;
      v = (L == 0) ? bih1[row] + bhh1[row]
                   : (L == 1) ? bih2[row] + bhh2[row] : bih3[row] + bhh3[row];
    }
    g_bias[pr] = v;
  }
  if (tid < H) g_wfc[tid] = Wfc[tid];
  if (tid == 0) g_wfc[30] = bfc[0];
}

__device__ __forceinline__ float sigx(float x) {
  return __builtin_amdgcn_rcpf(1.f + __builtin_amdgcn_exp2f(-x * LOG2E));
}
__device__ __forceinline__ float tanhx(float x) {
  float e = __builtin_amdgcn_exp2f(-x * (2.f * LOG2E));
  return fmaf(2.f, __builtin_amdgcn_rcpf(1.f + e), -1.f);
}
__device__ __forceinline__ unsigned int pack2(float a, float b, unsigned int& lo_out) {
  unsigned short ah, al, bh2, bl2;
  split16(a, ah, al);
  split16(b, bh2, bl2);
  lo_out = (unsigned int)al | ((unsigned int)bl2 << 16);
  return (unsigned int)ah | ((unsigned int)bh2 << 16);
}

// B k-map: 0..9 x | 10..39 h1 | 40..69 h2 | 70..99 h3 | 100..103 zero pad.
__global__ __launch_bounds__(256, 2) void lstm_main(const float* __restrict__ x,
                                                    float* __restrict__ out) {
  __shared__ unsigned int bh[2][52][32];  // hi f16 pairs [parity][k>>1][b]
  __shared__ unsigned int bl[2][52][32];  // lo f16 pairs

  const int tid = threadIdx.x;
  const int lane = tid & 63;
  const int wv = __builtin_amdgcn_readfirstlane(tid >> 6);  // mtile 0..3
  const int b32 = lane & 31;
  const int lh = lane >> 5;
  const int boff = lh * 128 + b32;  // word base within [k2][32]
  const int b0 = blockIdx.x * 32;

  unsigned int* bhf = &bh[0][0][0];
  unsigned int* blf = &bl[0][0][0];
  for (int i = tid; i < 2 * 52 * 32; i += 256) { bhf[i] = 0u; blf[i] = 0u; }

  // ---- persistent A fragments (hi/lo chains) + bias C-seeds
  f16x8 A1h[3], A1l[3], A2h[4], A2l[4], A3h[4], A3l[4];
#pragma unroll
  for (int s = 0; s < 3; ++s) {
    A1h[s] = __builtin_bit_cast(f16x8, *(const uint4*)&g_apack[A1_OFF + ((s * 4 + wv) * 2 + 0) * 256 + lane * 4]);
    A1l[s] = __builtin_bit_cast(f16x8, *(const uint4*)&g_apack[A1_OFF + ((s * 4 + wv) * 2 + 1) * 256 + lane * 4]);
  }
#pragma unroll
  for (int s = 0; s < 4; ++s) {
    A2h[s] = __builtin_bit_cast(f16x8, *(const uint4*)&g_apack[A2_OFF + ((s * 4 + wv) * 2 + 0) * 256 + lane * 4]);
    A2l[s] = __builtin_bit_cast(f16x8, *(const uint4*)&g_apack[A2_OFF + ((s * 4 + wv) * 2 + 1) * 256 + lane * 4]);
    A3h[s] = __builtin_bit_cast(f16x8, *(const uint4*)&g_apack[A3_OFF + ((s * 4 + wv) * 2 + 0) * 256 + lane * 4]);
    A3l[s] = __builtin_bit_cast(f16x8, *(const uint4*)&g_apack[A3_OFF + ((s * 4 + wv) * 2 + 1) * 256 + lane * 4]);
  }
  f32x16 bc1, bc2, bc3;
#pragma unroll
  for (int r = 0; r < 16; ++r) {
    int idx = wv * 32 + (r & 3) + 4 * lh + 8 * (r >> 2);
    bc1[r] = g_bias[idx];
    bc2[r] = g_bias[128 + idx];
    bc3[r] = g_bias[256 + idx];
  }

  float c1[4] = {0.f, 0.f, 0.f, 0.f};
  float c2[4] = {0.f, 0.f, 0.f, 0.f};
  float c3[4] = {0.f, 0.f, 0.f, 0.f};

  __syncthreads();  // LDS zeroed

  // stage x(0) into parity 1 (phase 0 reads rp=1)
  if (tid < 160) {
    const float* xp = x + (size_t)(b0 + (tid & 31)) * (T * F) + (tid >> 5) * 2;
    unsigned int wl, wh = pack2(xp[0], xp[1], wl);
    bh[1][tid >> 5][tid & 31] = wh;
    bl[1][tid >> 5][tid & 31] = wl;
  }
  __syncthreads();

#define GEMM_L(Z, AH, AL, BC, NS, KOFF2)                                   \
  {                                                                        \
    const int i0 = (KOFF2) * 32 + boff;                                    \
    uint4 uh = {BH[i0], BH[i0 + 32], BH[i0 + 64], BH[i0 + 96]};            \
    uint4 ul = {BL[i0], BL[i0 + 32], BL[i0 + 64], BL[i0 + 96]};            \
    f16x8 fbh = __builtin_bit_cast(f16x8, uh);                             \
    f16x8 fbl = __builtin_bit_cast(f16x8, ul);                             \
    Z = __builtin_amdgcn_mfma_f32_32x32x16_f16(AL[0], fbh, BC, 0, 0, 0);   \
    Z = __builtin_amdgcn_mfma_f32_32x32x16_f16(AH[0], fbl, Z, 0, 0, 0);    \
    Z = __builtin_amdgcn_mfma_f32_32x32x16_f16(AH[0], fbh, Z, 0, 0, 0);    \
    _Pragma("unroll") for (int s = 1; s < (NS); ++s) {                     \
      const int i1 = i0 + s * 8 * 32;                                      \
      uint4 vh = {BH[i1], BH[i1 + 32], BH[i1 + 64], BH[i1 + 96]};          \
      uint4 vl = {BL[i1], BL[i1 + 32], BL[i1 + 64], BL[i1 + 96]};          \
      f16x8 gh = __builtin_bit_cast(f16x8, vh);                            \
      f16x8 gl = __builtin_bit_cast(f16x8, vl);                            \
      Z = __builtin_amdgcn_mfma_f32_32x32x16_f16(AL[s], gh, Z, 0, 0, 0);   \
      Z = __builtin_amdgcn_mfma_f32_32x32x16_f16(AH[s], gl, Z, 0, 0, 0);   \
      Z = __builtin_amdgcn_mfma_f32_32x32x16_f16(AH[s], gh, Z, 0, 0, 0);   \
    }                                                                      \
  }

// C reg r: gate g = r>>2, unit u' = r&3; unit j = wv*8 + lh*4 + u'.
// h write: k = KOFF + wv*8 + lh*4 + up; unit-pairs packed into one u32 word.
#define UPD_L(Z, C, KOFF)                                                  \
  {                                                                        \
    float hv[4];                                                           \
    _Pragma("unroll") for (int up = 0; up < 4; ++up) {                     \
      float ii = sigx(Z[up]);                                              \
      float ff = sigx(Z[4 + up]);                                          \
      float gg = tanhx(Z[8 + up]);                                         \
      float oo = sigx(Z[12 + up]);                                         \
      float cc = fmaf(ff, C[up], ii * gg);                                 \
      C[up] = cc;                                                          \
      hv[up] = oo * tanhx(cc);                                             \
    }                                                                      \
    const int kw = (((KOFF) + wv * 8) >> 1) + lh * 2;                      \
    unsigned int wl0, wh0 = pack2(hv[0], hv[1], wl0);                      \
    unsigned int wl1, wh1 = pack2(hv[2], hv[3], wl1);                      \
    BHW[kw * 32 + b32] = wh0;                                              \
    BLW[kw * 32 + b32] = wl0;                                              \
    if (wv * 8 + lh * 4 + 2 < 30) {                                        \
      BHW[(kw + 1) * 32 + b32] = wh1;                                      \
      BLW[(kw + 1) * 32 + b32] = wl1;                                      \
    }                                                                      \
  }

  // Phase p: L1(t=p), L2(t=p-1), L3(t=p-2). Reads parity rp, writes wp.
#define DO_PHASE(P, L1A, L2A, L3A, PF)                                     \
  {                                                                        \
    const int wp = (P) & 1, rp = wp ^ 1;                                   \
    const unsigned int* BH = &bh[rp][0][0];                                \
    const unsigned int* BL = &bl[rp][0][0];                                \
    unsigned int* BHW = &bh[wp][0][0];                                     \
    unsigned int* BLW = &bl[wp][0][0];                                     \
    float xs0 = 0.f, xs1 = 0.f;                                            \
    if ((PF) && tid < 160) {                                               \
      const float* xp = x + (size_t)(b0 + (tid & 31)) * (T * F) +          \
                        ((P) + 1) * F + (tid >> 5) * 2;                    \
      xs0 = xp[0];                                                         \
      xs1 = xp[1];                                                         \
    }                                                                      \
    if (L1A) {                                                             \
      f32x16 z;                                                            \
      GEMM_L(z, A1h, A1l, bc1, 3, 0)                                       \
      UPD_L(z, c1, 10)                                                     \
    }                                                                      \
    if (L2A) {                                                             \
      f32x16 z;                                                            \
      GEMM_L(z, A2h, A2l, bc2, 4, 5)                                       \
      UPD_L(z, c2, 40)                                                     \
    }                                                                      \
    if (L3A) {                                                             \
      f32x16 z;                                                            \
      GEMM_L(z, A3h, A3l, bc3, 4, 20)                                      \
      UPD_L(z, c3, 70)                                                     \
    }                                                                      \
    if ((PF) && tid < 160) {                                               \
      unsigned int wl, wh = pack2(xs0, xs1, wl);                           \
      BHW[(tid >> 5) * 32 + (tid & 31)] = wh;                              \
      BLW[(tid >> 5) * 32 + (tid & 31)] = wl;                              \
    }                                                                      \
    __syncthreads();                                                       \
  }

  DO_PHASE(0, true, false, false, true)
  DO_PHASE(1, true, true, false, true)
  for (int p = 2; p < 199; ++p) DO_PHASE(p, true, true, true, true)
  DO_PHASE(199, true, true, true, false)
  DO_PHASE(200, false, true, true, false)
  DO_PHASE(201, false, false, true, false)

  // ---- FC epilogue: h3(199) written at phase 201 -> parity 1 (k 70..99).
  if (tid < 32) {
    const _Float16* H3h = (const _Float16*)&bh[1][0][0];
    const _Float16* H3l = (const _Float16*)&bl[1][0][0];
    float acc = g_wfc[30];
#pragma unroll
    for (int j = 0; j < H; ++j) {
      int k = 70 + j;
      int widx = ((k >> 1) * 32 + tid) * 2 + (k & 1);
      float hv = (float)H3h[widx] + (float)H3l[widx];
      acc = fmaf(hv, g_wfc[j], acc);
    }
    out[b0 + tid] = acc;
  }
}

extern "C" void kernel_launch(void* const* d_in, const int* in_sizes, int n_in,
                              void* d_out, int out_size, void* d_ws, size_t ws_size,
                              hipStream_t stream) {
  const float* x = (const float*)d_in[0];
  const float* Wih1 = (const float*)d_in[1];
  const float* Whh1 = (const float*)d_in[2];
  const float* bih1 = (const float*)d_in[3];
  const float* bhh1 = (const float*)d_in[4];
  const float* Wih2 = (const float*)d_in[5];
  const float* Whh2 = (const float*)d_in[6];
  const float* bih2 = (const float*)d_in[7];
  const float* bhh2 = (const float*)d_in[8];
  const float* Wih3 = (const float*)d_in[9];
  const float* Whh3 = (const float*)d_in[10];
  const float* bih3 = (const float*)d_in[11];
  const float* bhh3 = (const float*)d_in[12];
  const float* Wfc = (const float*)d_in[13];
  const float* bfc = (const float*)d_in[14];
  float* out = (float*)d_out;

  hipLaunchKernelGGL(lstm_prep, dim3(1), dim3(256), 0, stream,
                     Wih1, Whh1, bih1, bhh1, Wih2, Whh2, bih2, bhh2,
                     Wih3, Whh3, bih3, bhh3, Wfc, bfc);
  hipLaunchKernelGGL(lstm_main, dim3(B / 32), dim3(256), 0, stream, x, out);
}

// Round 10
// 567.685 us; speedup vs baseline: 6.5677x; 1.0220x over previous
//
#include <hip/hip_runtime.h>

// LSTM_84344567759011: 3-layer LSTM (B=16384, T=200, F=10, H=30) + FC(30->1), fp32.
//
// Round 10: round 9 with the cvt_pkrtz type fix (builtin returns __fp16x2,
// not _Float16x2 -- bit_cast at the boundary). Theory unchanged:
// phase interior reordered GEMM1/2/3 -> UPD1/2/3.
// r8 interleaved per-layer (GEMM->UPD)x3; UPD's ds_writes (parity wp) sit
// between layers' ds_reads (parity rp) and the compiler can't prove wp!=rp,
// so every layer's reads waited on the previous layer's writes (lgkmcnt) and
// each 9-12-long serial MFMA chain ran un-overlapped. Now: all ~88 ds_reads
// issue up front, the 3 independent MFMA chains interleave (3x matrix-pipe
// ILP), and the trans-heavy UPD tail overlaps the co-resident block's GEMMs.
// z1,z2,z3 (48 regs) live simultaneously -- fine on gfx950's unified file,
// MFMA accumulates in VGPRs natively (~220 total, under the 256/2-wave cap).
// Everything else identical to r8 (fragment layouts, hi/lo 3-term chains,
// unified B-buffer [k2][32], one barrier/phase, T14 x split).

#define LOG2E 1.44269504088896340736f

typedef _Float16 f16x8 __attribute__((ext_vector_type(8)));
typedef __fp16 fp16x2 __attribute__((ext_vector_type(2)));
typedef float f32x16 __attribute__((ext_vector_type(16)));

static constexpr int B = 16384;
static constexpr int T = 200;
static constexpr int F = 10;
static constexpr int H = 30;

static constexpr int A1_OFF = 0;      // 3 slices
static constexpr int A2_OFF = 6144;   // 4 slices
static constexpr int A3_OFF = 14336;  // 4 slices
__device__ unsigned int g_apack[22528];
__device__ float g_bias[384];  // [layer][mtile*32 + u + 4*lh + 8*g]
__device__ float g_wfc[31];

__device__ __forceinline__ void split16(float w, unsigned short& h, unsigned short& l) {
  _Float16 h16 = (_Float16)w;
  _Float16 l16 = (_Float16)(w - (float)h16);
  h = __builtin_bit_cast(unsigned short, h16);
  l = __builtin_bit_cast(unsigned short, l16);
}

#define PREP_LAYER(BASE, NS, FETCH)                                        \
  for (int idx = tid; idx < (NS)*4*64*4; idx += 256) {                     \
    int r = idx & 3, lane = (idx >> 2) & 63, m = (idx >> 8) & 3,           \
        s = idx >> 10;                                                     \
    int rl = lane & 31, kh = lane >> 5;                                    \
    int u = rl & 3, lh = (rl >> 2) & 1, g = rl >> 3;                       \
    int j = m * 8 + lh * 4 + u;                                            \
    unsigned int whi = 0, wlo = 0;                                         \
    for (int e = 0; e < 2; ++e) {                                          \
      int k = s * 16 + kh * 8 + r * 2 + e;                                 \
      float w = 0.f;                                                       \
      if (j < H) {                                                         \
        int row = g * H + j;                                               \
        w = FETCH;                                                         \
      }                                                                    \
      unsigned short hh, ll;                                               \
      split16(w, hh, ll);                                                  \
      whi |= (unsigned int)hh << (16 * e);                                 \
      wlo |= (unsigned int)ll << (16 * e);                                 \
    }                                                                      \
    int p0 = ((s * 4 + m) * 2) * 256 + lane * 4 + r;                       \
    g_apack[(BASE) + p0] = whi;                                            \
    g_apack[(BASE) + p0 + 256] = wlo;                                      \
  }

__global__ void lstm_prep(const float* __restrict__ Wih1, const float* __restrict__ Whh1,
                          const float* __restrict__ bih1, const float* __restrict__ bhh1,
                          const float* __restrict__ Wih2, const float* __restrict__ Whh2,
                          const float* __restrict__ bih2, const float* __restrict__ bhh2,
                          const float* __restrict__ Wih3, const float* __restrict__ Whh3,
                          const float* __restrict__ bih3, const float* __restrict__ bhh3,
                          const float* __restrict__ Wfc, const float* __restrict__ bfc) {
  const int tid = threadIdx.x;  // 256 threads, 1 block
  PREP_LAYER(A1_OFF, 3,
             (k < F ? Wih1[row * F + k] : (k < F + H ? Whh1[row * H + (k - F)] : 0.f)))
  PREP_LAYER(A2_OFF, 4,
             (k < H ? Wih2[row * H + k] : (k < 2 * H ? Whh2[row * H + (k - H)] : 0.f)))
  PREP_LAYER(A3_OFF, 4,
             (k < H ? Wih3[row * H + k] : (k < 2 * H ? Whh3[row * H + (k - H)] : 0.f)))
  for (int pr = tid; pr < 384; pr += 256) {
    int L = pr >> 7, rr = pr & 127;
    int m = rr >> 5, rl = rr & 31;
    int u = rl & 3, lh = (rl >> 2) & 1, g = rl >> 3;
    int j = m * 8 + lh * 4 + u;
    float v = 0.f;
    if (j < H) {
      int row = g * H + j;
      v = (L == 0) ? bih1[row] + bhh1[row]
                   : (L == 1) ? bih2[row] + bhh2[row] : bih3[row] + bhh3[row];
    }
    g_bias[pr] = v;
  }
  if (tid < H) g_wfc[tid] = Wfc[tid];
  if (tid == 0) g_wfc[30] = bfc[0];
}

__device__ __forceinline__ float sigx(float x) {
  return __builtin_amdgcn_rcpf(1.f + __builtin_amdgcn_exp2f(-x * LOG2E));
}
__device__ __forceinline__ float tanhx(float x) {
  float e = __builtin_amdgcn_exp2f(-x * (2.f * LOG2E));
  return fmaf(2.f, __builtin_amdgcn_rcpf(1.f + e), -1.f);
}

// Hot-path hi/lo f16 pair pack: hi via v_cvt_pkrtz (1 instr), lo = exact
// remainder re-packed. Residual error ~2^-22 relative, matches split16 class.
__device__ __forceinline__ unsigned int pack2(float a, float b, unsigned int& lo_out) {
  fp16x2 hp = __builtin_amdgcn_cvt_pkrtz(a, b);
  float la = a - (float)hp[0];
  float lb = b - (float)hp[1];
  fp16x2 lp = __builtin_amdgcn_cvt_pkrtz(la, lb);
  lo_out = __builtin_bit_cast(unsigned int, lp);
  return __builtin_bit_cast(unsigned int, hp);
}

// B k-map: 0..9 x | 10..39 h1 | 40..69 h2 | 70..99 h3 | 100..103 zero pad.
__global__ __launch_bounds__(256, 2) void lstm_main(const float* __restrict__ x,
                                                    float* __restrict__ out) {
  __shared__ unsigned int bh[2][52][32];  // hi f16 pairs [parity][k>>1][b]
  __shared__ unsigned int bl[2][52][32];  // lo f16 pairs

  const int tid = threadIdx.x;
  const int lane = tid & 63;
  const int wv = __builtin_amdgcn_readfirstlane(tid >> 6);  // mtile 0..3
  const int b32 = lane & 31;
  const int lh = lane >> 5;
  const int boff = lh * 128 + b32;  // word base within [k2][32]
  const int b0 = blockIdx.x * 32;

  unsigned int* bhf = &bh[0][0][0];
  unsigned int* blf = &bl[0][0][0];
  for (int i = tid; i < 2 * 52 * 32; i += 256) { bhf[i] = 0u; blf[i] = 0u; }

  // ---- persistent A fragments (hi/lo chains) + bias C-seeds
  f16x8 A1h[3], A1l[3], A2h[4], A2l[4], A3h[4], A3l[4];
#pragma unroll
  for (int s = 0; s < 3; ++s) {
    A1h[s] = __builtin_bit_cast(f16x8, *(const uint4*)&g_apack[A1_OFF + ((s * 4 + wv) * 2 + 0) * 256 + lane * 4]);
    A1l[s] = __builtin_bit_cast(f16x8, *(const uint4*)&g_apack[A1_OFF + ((s * 4 + wv) * 2 + 1) * 256 + lane * 4]);
  }
#pragma unroll
  for (int s = 0; s < 4; ++s) {
    A2h[s] = __builtin_bit_cast(f16x8, *(const uint4*)&g_apack[A2_OFF + ((s * 4 + wv) * 2 + 0) * 256 + lane * 4]);
    A2l[s] = __builtin_bit_cast(f16x8, *(const uint4*)&g_apack[A2_OFF + ((s * 4 + wv) * 2 + 1) * 256 + lane * 4]);
    A3h[s] = __builtin_bit_cast(f16x8, *(const uint4*)&g_apack[A3_OFF + ((s * 4 + wv) * 2 + 0) * 256 + lane * 4]);
    A3l[s] = __builtin_bit_cast(f16x8, *(const uint4*)&g_apack[A3_OFF + ((s * 4 + wv) * 2 + 1) * 256 + lane * 4]);
  }
  f32x16 bc1, bc2, bc3;
#pragma unroll
  for (int r = 0; r < 16; ++r) {
    int idx = wv * 32 + (r & 3) + 4 * lh + 8 * (r >> 2);
    bc1[r] = g_bias[idx];
    bc2[r] = g_bias[128 + idx];
    bc3[r] = g_bias[256 + idx];
  }

  float c1[4] = {0.f, 0.f, 0.f, 0.f};
  float c2[4] = {0.f, 0.f, 0.f, 0.f};
  float c3[4] = {0.f, 0.f, 0.f, 0.f};

  __syncthreads();  // LDS zeroed

  // stage x(0) into parity 1 (phase 0 reads rp=1)
  if (tid < 160) {
    const float* xp = x + (size_t)(b0 + (tid & 31)) * (T * F) + (tid >> 5) * 2;
    unsigned int wl, wh = pack2(xp[0], xp[1], wl);
    bh[1][tid >> 5][tid & 31] = wh;
    bl[1][tid >> 5][tid & 31] = wl;
  }
  __syncthreads();

#define GEMM_L(Z, AH, AL, BC, NS, KOFF2)                                   \
  {                                                                        \
    const int i0 = (KOFF2) * 32 + boff;                                    \
    uint4 uh = {BH[i0], BH[i0 + 32], BH[i0 + 64], BH[i0 + 96]};            \
    uint4 ul = {BL[i0], BL[i0 + 32], BL[i0 + 64], BL[i0 + 96]};            \
    f16x8 fbh = __builtin_bit_cast(f16x8, uh);                             \
    f16x8 fbl = __builtin_bit_cast(f16x8, ul);                             \
    Z = __builtin_amdgcn_mfma_f32_32x32x16_f16(AL[0], fbh, BC, 0, 0, 0);   \
    Z = __builtin_amdgcn_mfma_f32_32x32x16_f16(AH[0], fbl, Z, 0, 0, 0);    \
    Z = __builtin_amdgcn_mfma_f32_32x32x16_f16(AH[0], fbh, Z, 0, 0, 0);    \
    _Pragma("unroll") for (int s = 1; s < (NS); ++s) {                     \
      const int i1 = i0 + s * 8 * 32;                                      \
      uint4 vh = {BH[i1], BH[i1 + 32], BH[i1 + 64], BH[i1 + 96]};          \
      uint4 vl = {BL[i1], BL[i1 + 32], BL[i1 + 64], BL[i1 + 96]};          \
      f16x8 gh = __builtin_bit_cast(f16x8, vh);                            \
      f16x8 gl = __builtin_bit_cast(f16x8, vl);                            \
      Z = __builtin_amdgcn_mfma_f32_32x32x16_f16(AL[s], gh, Z, 0, 0, 0);   \
      Z = __builtin_amdgcn_mfma_f32_32x32x16_f16(AH[s], gl, Z, 0, 0, 0);   \
      Z = __builtin_amdgcn_mfma_f32_32x32x16_f16(AH[s], gh, Z, 0, 0, 0);   \
    }                                                                      \
  }

// C reg r: gate g = r>>2, unit u' = r&3; unit j = wv*8 + lh*4 + u'.
#define UPD_L(Z, C, KOFF)                                                  \
  {                                                                        \
    float hv[4];                                                           \
    _Pragma("unroll") for (int up = 0; up < 4; ++up) {                     \
      float ii = sigx(Z[up]);                                              \
      float ff = sigx(Z[4 + up]);                                          \
      float gg = tanhx(Z[8 + up]);                                         \
      float oo = sigx(Z[12 + up]);                                         \
      float cc = fmaf(ff, C[up], ii * gg);                                 \
      C[up] = cc;                                                          \
      hv[up] = oo * tanhx(cc);                                             \
    }                                                                      \
    const int kw = (((KOFF) + wv * 8) >> 1) + lh * 2;                      \
    unsigned int wl0, wh0 = pack2(hv[0], hv[1], wl0);                      \
    unsigned int wl1, wh1 = pack2(hv[2], hv[3], wl1);                      \
    BHW[kw * 32 + b32] = wh0;                                              \
    BLW[kw * 32 + b32] = wl0;                                              \
    if (wv * 8 + lh * 4 + 2 < 30) {                                        \
      BHW[(kw + 1) * 32 + b32] = wh1;                                      \
      BLW[(kw + 1) * 32 + b32] = wl1;                                      \
    }                                                                      \
  }

  // Phase p: L1(t=p), L2(t=p-1), L3(t=p-2). ALL GEMMs (reads, parity rp)
  // first -> 3 independent MFMA chains interleave; then ALL UPDs (writes,
  // parity wp); then x-write; one barrier.
#define DO_PHASE(P, L1A, L2A, L3A, PF)                                     \
  {                                                                        \
    const int wp = (P) & 1, rp = wp ^ 1;                                   \
    const unsigned int* BH = &bh[rp][0][0];                                \
    const unsigned int* BL = &bl[rp][0][0];                                \
    unsigned int* BHW = &bh[wp][0][0];                                     \
    unsigned int* BLW = &bl[wp][0][0];                                     \
    float xs0 = 0.f, xs1 = 0.f;                                            \
    if ((PF) && tid < 160) {                                               \
      const float* xp = x + (size_t)(b0 + (tid & 31)) * (T * F) +          \
                        ((P) + 1) * F + (tid >> 5) * 2;                    \
      xs0 = xp[0];                                                         \
      xs1 = xp[1];                                                         \
    }                                                                      \
    f32x16 z1, z2, z3;                                                     \
    if (L1A) { GEMM_L(z1, A1h, A1l, bc1, 3, 0) }                           \
    if (L2A) { GEMM_L(z2, A2h, A2l, bc2, 4, 5) }                           \
    if (L3A) { GEMM_L(z3, A3h, A3l, bc3, 4, 20) }                          \
    if (L1A) { UPD_L(z1, c1, 10) }                                         \
    if (L2A) { UPD_L(z2, c2, 40) }                                         \
    if (L3A) { UPD_L(z3, c3, 70) }                                         \
    if ((PF) && tid < 160) {                                               \
      unsigned int wl, wh = pack2(xs0, xs1, wl);                           \
      BHW[(tid >> 5) * 32 + (tid & 31)] = wh;                              \
      BLW[(tid >> 5) * 32 + (tid & 31)] = wl;                              \
    }                                                                      \
    __syncthreads();                                                       \
  }

  DO_PHASE(0, true, false, false, true)
  DO_PHASE(1, true, true, false, true)
  for (int p = 2; p < 199; ++p) DO_PHASE(p, true, true, true, true)
  DO_PHASE(199, true, true, true, false)
  DO_PHASE(200, false, true, true, false)
  DO_PHASE(201, false, false, true, false)

  // ---- FC epilogue: h3(199) written at phase 201 -> parity 1 (k 70..99).
  if (tid < 32) {
    const _Float16* H3h = (const _Float16*)&bh[1][0][0];
    const _Float16* H3l = (const _Float16*)&bl[1][0][0];
    float acc = g_wfc[30];
#pragma unroll
    for (int j = 0; j < H; ++j) {
      int k = 70 + j;
      int widx = ((k >> 1) * 32 + tid) * 2 + (k & 1);
      float hv = (float)H3h[widx] + (float)H3l[widx];
      acc = fmaf(hv, g_wfc[j], acc);
    }
    out[b0 + tid] = acc;
  }
}

extern "C" void kernel_launch(void* const* d_in, const int* in_sizes, int n_in,
                              void* d_out, int out_size, void* d_ws, size_t ws_size,
                              hipStream_t stream) {
  const float* x = (const float*)d_in[0];
  const float* Wih1 = (const float*)d_in[1];
  const float* Whh1 = (const float*)d_in[2];
  const float* bih1 = (const float*)d_in[3];
  const float* bhh1 = (const float*)d_in[4];
  const float* Wih2 = (const float*)d_in[5];
  const float* Whh2 = (const float*)d_in[6];
  const float* bih2 = (const float*)d_in[7];
  const float* bhh2 = (const float*)d_in[8];
  const float* Wih3 = (const float*)d_in[9];
  const float* Whh3 = (const float*)d_in[10];
  const float* bih3 = (const float*)d_in[11];
  const float* bhh3 = (const float*)d_in[12];
  const float* Wfc = (const float*)d_in[13];
  const float* bfc = (const float*)d_in[14];
  float* out = (float*)d_out;

  hipLaunchKernelGGL(lstm_prep, dim3(1), dim3(256), 0, stream,
                     Wih1, Whh1, bih1, bhh1, Wih2, Whh2, bih2, bhh2,
                     Wih3, Whh3, bih3, bhh3, Wfc, bfc);
  hipLaunchKernelGGL(lstm_main, dim3(B / 32), dim3(256), 0, stream, x, out);
}

// Round 11
// 563.149 us; speedup vs baseline: 6.6206x; 1.0081x over previous
//
#include <hip/hip_runtime.h>

// LSTM_84344567759011: 3-layer LSTM (B=16384, T=200, F=10, H=30) + FC(30->1), fp32.
//
// Round 11: 16x16x32 MFMA restructure for 2x occupancy. Grid was the
// occupancy binder (512 blocks = 2/CU = 2 waves/SIMD, 35% idle). Now:
// 1024 blocks x 16 batch, 4 blocks/CU = 16 waves/CU. Wave = 2 M-tiles of 16
// gate rows (tile t = units 4t..4t+3; packed row = 4u'+g so lane's 4 C regs
// = 4 gates of unit (lane>>4) -> thread-local UPD, 6 units/thread).
// Precision: W in f16 (hi only -- Wlo·Hhi chain dropped to fit 128 VGPR;
// +~5e-5 rms z error), h split hi/lo f16: z = Whi·Hhi + Whi·Hlo, 2 MFMA per
// K-slice, 24 MFMA/wave/phase. B-buffer [k2][PITCH=20] (rg-groups 2-way
// bank split = free). Layer-pipelined phases (one barrier), T14 x split.

#define LOG2E 1.44269504088896340736f

typedef _Float16 f16x8 __attribute__((ext_vector_type(8)));
typedef __fp16 fp16x2 __attribute__((ext_vector_type(2)));
typedef float f32x4 __attribute__((ext_vector_type(4)));

static constexpr int B = 16384;
static constexpr int T = 200;
static constexpr int F = 10;
static constexpr int H = 30;
static constexpr int PITCH = 20;  // u32 per k2 row (16 cols + 4 pad)
static constexpr int NK2 = 52;    // k = [x:0..9 | h1:10..39 | h2:40..69 | h3:70..99 | pad]

// A-pack (hi-f16 only): per layer 2 slices x 8 tiles x 256 u32.
static constexpr int AL1 = 0;
static constexpr int AL2 = 4096;
static constexpr int AL3 = 8192;
__device__ unsigned int g_apack[12288];
__device__ float g_bias[384];  // [L][tile*16 + 4u' + g]
__device__ float g_wfc[31];

// A frag (16x16x32): lane l holds row=l&15, k=(l>>4)*8 + r*2 + e.
// Packed row = 4u' + g (u'=row>>2 local unit, g=row&3 gate); j = t*4+u'.
#define PREP_LAYER(BASE, FETCH)                                            \
  for (int idx = tid; idx < 4096; idx += 256) {                            \
    int r = idx & 3, lane = (idx >> 2) & 63, t = (idx >> 8) & 7,           \
        s = idx >> 11;                                                     \
    int rl = lane & 15, rg = lane >> 4;                                    \
    int u = rl >> 2, g = rl & 3;                                           \
    int j = t * 4 + u;                                                     \
    unsigned int whi = 0;                                                  \
    for (int e = 0; e < 2; ++e) {                                          \
      int k = s * 32 + rg * 8 + r * 2 + e;                                 \
      float w = 0.f;                                                       \
      if (j < H) {                                                         \
        int row = g * H + j;                                               \
        w = FETCH;                                                         \
      }                                                                    \
      _Float16 h16 = (_Float16)w;                                          \
      whi |= (unsigned int)__builtin_bit_cast(unsigned short, h16)         \
             << (16 * e);                                                  \
    }                                                                      \
    g_apack[(BASE) + (s * 8 + t) * 256 + lane * 4 + r] = whi;              \
  }

__global__ void lstm_prep(const float* __restrict__ Wih1, const float* __restrict__ Whh1,
                          const float* __restrict__ bih1, const float* __restrict__ bhh1,
                          const float* __restrict__ Wih2, const float* __restrict__ Whh2,
                          const float* __restrict__ bih2, const float* __restrict__ bhh2,
                          const float* __restrict__ Wih3, const float* __restrict__ Whh3,
                          const float* __restrict__ bih3, const float* __restrict__ bhh3,
                          const float* __restrict__ Wfc, const float* __restrict__ bfc) {
  const int tid = threadIdx.x;  // 256 threads, 1 block
  // L1 window k 0..63 (global): 0..9 x -> Wih1, 10..39 h1 -> Whh1, else 0
  PREP_LAYER(AL1, (k < F ? Wih1[row * F + k]
                         : (k < F + H ? Whh1[row * H + (k - F)] : 0.f)))
  // L2 window local 0..63 = global 10..73: 0..29 h1 -> Wih2, 30..59 h2 -> Whh2
  PREP_LAYER(AL2, (k < H ? Wih2[row * H + k]
                         : (k < 2 * H ? Whh2[row * H + (k - H)] : 0.f)))
  // L3 window local 0..63 = global 40..103: 0..29 h2 -> Wih3, 30..59 h3 -> Whh3
  PREP_LAYER(AL3, (k < H ? Wih3[row * H + k]
                         : (k < 2 * H ? Whh3[row * H + (k - H)] : 0.f)))
  for (int pr = tid; pr < 384; pr += 256) {
    int L = pr >> 7, rr = pr & 127;
    int t = rr >> 4, rl = rr & 15;
    int u = rl >> 2, g = rl & 3;
    int j = t * 4 + u;
    float v = 0.f;
    if (j < H) {
      int row = g * H + j;
      v = (L == 0) ? bih1[row] + bhh1[row]
                   : (L == 1) ? bih2[row] + bhh2[row] : bih3[row] + bhh3[row];
    }
    g_bias[pr] = v;
  }
  if (tid < H) g_wfc[tid] = Wfc[tid];
  if (tid == 0) g_wfc[30] = bfc[0];
}

__device__ __forceinline__ float sigx(float x) {
  return __builtin_amdgcn_rcpf(1.f + __builtin_amdgcn_exp2f(-x * LOG2E));
}
__device__ __forceinline__ float tanhx(float x) {
  float e = __builtin_amdgcn_exp2f(-x * (2.f * LOG2E));
  return fmaf(2.f, __builtin_amdgcn_rcpf(1.f + e), -1.f);
}
__device__ __forceinline__ unsigned int pack2(float a, float b, unsigned int& lo_out) {
  fp16x2 hp = __builtin_amdgcn_cvt_pkrtz(a, b);
  float la = a - (float)hp[0];
  float lb = b - (float)hp[1];
  fp16x2 lp = __builtin_amdgcn_cvt_pkrtz(la, lb);
  lo_out = __builtin_bit_cast(unsigned int, lp);
  return __builtin_bit_cast(unsigned int, hp);
}

__global__ __launch_bounds__(256, 4) void lstm_main(const float* __restrict__ x,
                                                    float* __restrict__ out) {
  __shared__ unsigned int bh[2][NK2 * PITCH];  // hi f16 pairs [parity][k2*PITCH+col]
  __shared__ unsigned int bl[2][NK2 * PITCH];  // lo f16 pairs

  const int tid = threadIdx.x;
  const int lane = tid & 63;
  const int wv = __builtin_amdgcn_readfirstlane(tid >> 6);  // 0..3
  const int col = lane & 15;                                // batch col
  const int rg = (lane >> 4) & 3;
  const int b0 = blockIdx.x * 16;

  for (int i = tid; i < 2 * NK2 * PITCH; i += 256) {
    (&bh[0][0])[i] = 0u;
    (&bl[0][0])[i] = 0u;
  }

  // ---- persistent A fragments (wave's 2 tiles) + bias C-seeds
  f16x8 A1[2][2], A2[2][2], A3[2][2];  // [slice][tile]
#pragma unroll
  for (int s = 0; s < 2; ++s)
#pragma unroll
    for (int ti = 0; ti < 2; ++ti) {
      int t = 2 * wv + ti;
      A1[s][ti] = __builtin_bit_cast(f16x8, *(const uint4*)&g_apack[AL1 + (s * 8 + t) * 256 + lane * 4]);
      A2[s][ti] = __builtin_bit_cast(f16x8, *(const uint4*)&g_apack[AL2 + (s * 8 + t) * 256 + lane * 4]);
      A3[s][ti] = __builtin_bit_cast(f16x8, *(const uint4*)&g_apack[AL3 + (s * 8 + t) * 256 + lane * 4]);
    }
  f32x4 BC1[2], BC2[2], BC3[2];
#pragma unroll
  for (int ti = 0; ti < 2; ++ti) {
    int t = 2 * wv + ti;
    BC1[ti] = *(const f32x4*)&g_bias[0 + t * 16 + rg * 4];
    BC2[ti] = *(const f32x4*)&g_bias[128 + t * 16 + rg * 4];
    BC3[ti] = *(const f32x4*)&g_bias[256 + t * 16 + rg * 4];
  }

  float c1[2] = {0.f, 0.f};
  float c2[2] = {0.f, 0.f};
  float c3[2] = {0.f, 0.f};

  __syncthreads();  // LDS zeroed

  // stage x(0) into parity 1 (phase 0 reads rp=1)
  if (tid < 80) {
    const float* xp = x + (size_t)(b0 + (tid & 15)) * (T * F) + (tid >> 4) * 2;
    unsigned int wl, wh = pack2(xp[0], xp[1], wl);
    bh[1][(tid >> 4) * PITCH + (tid & 15)] = wh;
    bl[1][(tid >> 4) * PITCH + (tid & 15)] = wl;
  }
  __syncthreads();

// 2 slices x (Whi*Hlo + Whi*Hhi) per tile; B shared across the 2 tiles.
#define GEMM_L(Z0, Z1, A_, BC_, KOFF2)                                     \
  {                                                                        \
    const int i0 = ((KOFF2) + rg * 4) * PITCH + col;                       \
    const int i1 = i0 + 16 * PITCH;                                        \
    uint4 uh0 = {BH[i0], BH[i0 + PITCH], BH[i0 + 2 * PITCH], BH[i0 + 3 * PITCH]}; \
    uint4 ul0 = {BL[i0], BL[i0 + PITCH], BL[i0 + 2 * PITCH], BL[i0 + 3 * PITCH]}; \
    uint4 uh1 = {BH[i1], BH[i1 + PITCH], BH[i1 + 2 * PITCH], BH[i1 + 3 * PITCH]}; \
    uint4 ul1 = {BL[i1], BL[i1 + PITCH], BL[i1 + 2 * PITCH], BL[i1 + 3 * PITCH]}; \
    f16x8 fh0 = __builtin_bit_cast(f16x8, uh0);                            \
    f16x8 fl0 = __builtin_bit_cast(f16x8, ul0);                            \
    f16x8 fh1 = __builtin_bit_cast(f16x8, uh1);                            \
    f16x8 fl1 = __builtin_bit_cast(f16x8, ul1);                            \
    Z0 = __builtin_amdgcn_mfma_f32_16x16x32_f16(A_[0][0], fl0, BC_[0], 0, 0, 0); \
    Z0 = __builtin_amdgcn_mfma_f32_16x16x32_f16(A_[0][0], fh0, Z0, 0, 0, 0);     \
    Z0 = __builtin_amdgcn_mfma_f32_16x16x32_f16(A_[1][0], fl1, Z0, 0, 0, 0);     \
    Z0 = __builtin_amdgcn_mfma_f32_16x16x32_f16(A_[1][0], fh1, Z0, 0, 0, 0);     \
    Z1 = __builtin_amdgcn_mfma_f32_16x16x32_f16(A_[0][1], fl0, BC_[1], 0, 0, 0); \
    Z1 = __builtin_amdgcn_mfma_f32_16x16x32_f16(A_[0][1], fh0, Z1, 0, 0, 0);     \
    Z1 = __builtin_amdgcn_mfma_f32_16x16x32_f16(A_[1][1], fl1, Z1, 0, 0, 0);     \
    Z1 = __builtin_amdgcn_mfma_f32_16x16x32_f16(A_[1][1], fh1, Z1, 0, 0, 0);     \
  }

// C regs of tile: row = 4*rg + r -> unit j = t*4 + rg, gate = r (i,f,g,o).
#define UPD2(Z0, Z1, C, KOFF)                                              \
  {                                                                        \
    {                                                                      \
      float ii = sigx(Z0[0]), ff = sigx(Z0[1]);                            \
      float gg = tanhx(Z0[2]), oo = sigx(Z0[3]);                           \
      float cc = fmaf(ff, C[0], ii * gg);                                  \
      C[0] = cc;                                                           \
      float hv = oo * tanhx(cc);                                           \
      int j = 8 * wv + rg;                                                 \
      if (j < H) {                                                         \
        int k = (KOFF) + j;                                                \
        int hwi = ((k >> 1) * PITCH + col) * 2 + (k & 1);                  \
        _Float16 h16 = (_Float16)hv;                                       \
        ((_Float16*)BHW)[hwi] = h16;                                       \
        ((_Float16*)BLW)[hwi] = (_Float16)(hv - (float)h16);               \
      }                                                                    \
    }                                                                      \
    {                                                                      \
      float ii = sigx(Z1[0]), ff = sigx(Z1[1]);                            \
      float gg = tanhx(Z1[2]), oo = sigx(Z1[3]);                           \
      float cc = fmaf(ff, C[1], ii * gg);                                  \
      C[1] = cc;                                                           \
      float hv = oo * tanhx(cc);                                           \
      int j = 8 * wv + 4 + rg;                                             \
      if (j < H) {                                                         \
        int k = (KOFF) + j;                                                \
        int hwi = ((k >> 1) * PITCH + col) * 2 + (k & 1);                  \
        _Float16 h16 = (_Float16)hv;                                       \
        ((_Float16*)BHW)[hwi] = h16;                                       \
        ((_Float16*)BLW)[hwi] = (_Float16)(hv - (float)h16);               \
      }                                                                    \
    }                                                                      \
  }

  // Phase p: L1(t=p), L2(t=p-1), L3(t=p-2). Reads parity rp, writes wp.
#define DO_PHASE(P, L1A, L2A, L3A, PF)                                     \
  {                                                                        \
    const int wp = (P) & 1, rp = wp ^ 1;                                   \
    const unsigned int* BH = bh[rp];                                       \
    const unsigned int* BL = bl[rp];                                       \
    unsigned int* BHW = bh[wp];                                            \
    unsigned int* BLW = bl[wp];                                            \
    float xs0 = 0.f, xs1 = 0.f;                                            \
    if ((PF) && tid < 80) {                                                \
      const float* xp = x + (size_t)(b0 + (tid & 15)) * (T * F) +          \
                        ((P) + 1) * F + (tid >> 4) * 2;                    \
      xs0 = xp[0];                                                         \
      xs1 = xp[1];                                                         \
    }                                                                      \
    if (L1A) {                                                             \
      f32x4 z0, z1;                                                        \
      GEMM_L(z0, z1, A1, BC1, 0)                                           \
      UPD2(z0, z1, c1, 10)                                                 \
    }                                                                      \
    if (L2A) {                                                             \
      f32x4 z0, z1;                                                        \
      GEMM_L(z0, z1, A2, BC2, 5)                                           \
      UPD2(z0, z1, c2, 40)                                                 \
    }                                                                      \
    if (L3A) {                                                             \
      f32x4 z0, z1;                                                        \
      GEMM_L(z0, z1, A3, BC3, 20)                                          \
      UPD2(z0, z1, c3, 70)                                                 \
    }                                                                      \
    if ((PF) && tid < 80) {                                                \
      unsigned int wl, wh = pack2(xs0, xs1, wl);                           \
      BHW[(tid >> 4) * PITCH + (tid & 15)] = wh;                           \
      BLW[(tid >> 4) * PITCH + (tid & 15)] = wl;                           \
    }                                                                      \
    __syncthreads();                                                       \
  }

  DO_PHASE(0, true, false, false, true)
  DO_PHASE(1, true, true, false, true)
  for (int p = 2; p < 199; ++p) DO_PHASE(p, true, true, true, true)
  DO_PHASE(199, true, true, true, false)
  DO_PHASE(200, false, true, true, false)
  DO_PHASE(201, false, false, true, false)

  // ---- FC epilogue: h3(199) written at phase 201 -> parity 1 (k 70..99).
  if (tid < 16) {
    const _Float16* Hh = (const _Float16*)bh[1];
    const _Float16* Hl = (const _Float16*)bl[1];
    float acc = g_wfc[30];
#pragma unroll
    for (int j = 0; j < H; ++j) {
      int k = 70 + j;
      int hwi = ((k >> 1) * PITCH + tid) * 2 + (k & 1);
      float hv = (float)Hh[hwi] + (float)Hl[hwi];
      acc = fmaf(hv, g_wfc[j], acc);
    }
    out[b0 + tid] = acc;
  }
}

extern "C" void kernel_launch(void* const* d_in, const int* in_sizes, int n_in,
                              void* d_out, int out_size, void* d_ws, size_t ws_size,
                              hipStream_t stream) {
  const float* x = (const float*)d_in[0];
  const float* Wih1 = (const float*)d_in[1];
  const float* Whh1 = (const float*)d_in[2];
  const float* bih1 = (const float*)d_in[3];
  const float* bhh1 = (const float*)d_in[4];
  const float* Wih2 = (const float*)d_in[5];
  const float* Whh2 = (const float*)d_in[6];
  const float* bih2 = (const float*)d_in[7];
  const float* bhh2 = (const float*)d_in[8];
  const float* Wih3 = (const float*)d_in[9];
  const float* Whh3 = (const float*)d_in[10];
  const float* bih3 = (const float*)d_in[11];
  const float* bhh3 = (const float*)d_in[12];
  const float* Wfc = (const float*)d_in[13];
  const float* bfc = (const float*)d_in[14];
  float* out = (float*)d_out;

  hipLaunchKernelGGL(lstm_prep, dim3(1), dim3(256), 0, stream,
                     Wih1, Whh1, bih1, bhh1, Wih2, Whh2, bih2, bhh2,
                     Wih3, Whh3, bih3, bhh3, Wfc, bfc);
  hipLaunchKernelGGL(lstm_main, dim3(B / 16), dim3(256), 0, stream, x, out);
}